// Round 7
// baseline (739.973 us; speedup 1.0000x reference)
//
#include <hip/hip_runtime.h>
#include <stdint.h>

#define N_NODES 50000
#define N_EDGES 800000
#define FEAT 128
#define HID 128
#define NCLS 10
#define NGRAPH 64

// ---------------- init: zero counters/accumulators (ws is poisoned 0xAA) ---
__global__ void k_init(int* cnt, int* counts, float* sums, float* maxs) {
    int i = blockIdx.x * 256 + threadIdx.x;
    if (i < N_NODES) cnt[i] = 0;
    if (i < NGRAPH) counts[i] = 0;
    if (i < NGRAPH * HID) { sums[i] = 0.f; maxs[i] = 0.f; }
}

// ---------------- degree histogram over dst ----------------
__global__ void k_count_edges(const int* __restrict__ dst, int* cnt) {
    int i = blockIdx.x * 256 + threadIdx.x;
    if (i < N_EDGES) atomicAdd(&cnt[dst[i]], 1);
}

__global__ void k_isd(const int* __restrict__ cnt, float* isd) {
    int i = blockIdx.x * 256 + threadIdx.x;
    if (i < N_NODES) isd[i] = 1.0f / sqrtf((float)cnt[i] + 1.0f);
}

// ---------------- two-level exclusive scan of cnt -> rowp ----------------
__global__ void k_scanA(const int* __restrict__ cnt, int* rowp, int* bsum) {
    __shared__ int s[1024];
    int t = threadIdx.x;
    int i = blockIdx.x * 1024 + t;
    int v = (i < N_NODES) ? cnt[i] : 0;
    s[t] = v;
    __syncthreads();
    for (int o = 1; o < 1024; o <<= 1) {
        int x = (t >= o) ? s[t - o] : 0;
        __syncthreads();
        s[t] += x;
        __syncthreads();
    }
    if (i < N_NODES) rowp[i] = s[t] - v;       // local exclusive
    if (t == 1023) bsum[blockIdx.x] = s[t];    // block total
}

__global__ void k_scanB(int* bsum) {  // 49 block sums -> exclusive offsets
    int t = threadIdx.x;
    int v = (t < 49) ? bsum[t] : 0;
    int orig = v;
    for (int o = 1; o < 64; o <<= 1) {
        int y = __shfl_up(v, o);
        if (t >= o) v += y;
    }
    if (t < 49) bsum[t] = v - orig;
}

__global__ void k_scanC(int* rowp, const int* __restrict__ bsum, int* nxt) {
    int i = blockIdx.x * 256 + threadIdx.x;
    if (i < N_NODES) {
        int r = rowp[i] + bsum[i >> 10];
        rowp[i] = r;
        nxt[i] = r;
    }
}

__global__ void k_fill(const int* __restrict__ src, const int* __restrict__ dst,
                       int* nxt, int* csr) {
    int i = blockIdx.x * 256 + threadIdx.x;
    if (i < N_EDGES) {
        int d = dst[i];
        int p = atomicAdd(&nxt[d], 1);
        csr[p] = src[i];
    }
}

// ---------------- GEMM: O[i][:] = isd[i] * (A[i][:] @ W)  (fp32 vector) ----
__device__ __forceinline__ void fma4(float4& a, float s, const float4& w) {
    a.x = fmaf(s, w.x, a.x); a.y = fmaf(s, w.y, a.y);
    a.z = fmaf(s, w.z, a.z); a.w = fmaf(s, w.w, a.w);
}

__global__ void k_gemm(const float* __restrict__ A, const float* __restrict__ W,
                       const float* __restrict__ isd, float* __restrict__ O) {
    __shared__ float Xs[8][64];
    __shared__ float Ws[8][128];
    int t = threadIdx.x;
    int row0 = blockIdx.x * 64;
    int tr = (t >> 5) << 3;   // 8 rows per thread
    int tc = (t & 31) << 2;   // 4 cols per thread
    float4 acc[8];
#pragma unroll
    for (int j = 0; j < 8; j++) acc[j] = make_float4(0.f, 0.f, 0.f, 0.f);

    for (int k0 = 0; k0 < 128; k0 += 8) {
        int e = t * 2;
        int xr = e >> 3, xk = e & 7;
        int gr = row0 + xr;
        float2 xv = make_float2(0.f, 0.f);
        if (gr < N_NODES) xv = *(const float2*)(A + (size_t)gr * 128 + k0 + xk);
        Xs[xk][xr] = xv.x;
        Xs[xk + 1][xr] = xv.y;
        int we = t * 4;
        int wk = we >> 7, wc = we & 127;
        float4 wv4 = *(const float4*)(W + (size_t)(k0 + wk) * 128 + wc);
        Ws[wk][wc + 0] = wv4.x;
        Ws[wk][wc + 1] = wv4.y;
        Ws[wk][wc + 2] = wv4.z;
        Ws[wk][wc + 3] = wv4.w;
        __syncthreads();
#pragma unroll
        for (int kk = 0; kk < 8; kk++) {
            float4 xa = *(const float4*)&Xs[kk][tr];
            float4 xb = *(const float4*)&Xs[kk][tr + 4];
            float4 wv = *(const float4*)&Ws[kk][tc];
            fma4(acc[0], xa.x, wv); fma4(acc[1], xa.y, wv);
            fma4(acc[2], xa.z, wv); fma4(acc[3], xa.w, wv);
            fma4(acc[4], xb.x, wv); fma4(acc[5], xb.y, wv);
            fma4(acc[6], xb.z, wv); fma4(acc[7], xb.w, wv);
        }
        __syncthreads();
    }
#pragma unroll
    for (int j = 0; j < 8; j++) {
        int r = row0 + tr + j;
        if (r < N_NODES) {
            float sc = isd[r];
            float4 o = acc[j];
            o.x *= sc; o.y *= sc; o.z *= sc; o.w *= sc;
            *(float4*)(O + (size_t)r * 128 + tc) = o;
        }
    }
}

// ---------------- aggregation: h[i] = relu(isd[i]*(sum hp[src] + hp[i]) + b)
__global__ void k_agg(const float* __restrict__ hp, const int* __restrict__ csr,
                      const int* __restrict__ rowp, const int* __restrict__ cnt,
                      const float* __restrict__ isd, const float* __restrict__ bias,
                      float* __restrict__ out) {
    int wid = threadIdx.x >> 6;
    int lane = threadIdx.x & 63;
    int i = blockIdx.x * 4 + wid;
    if (i >= N_NODES) return;
    int start = rowp[i];
    int m = cnt[i];
    float2 self = *(const float2*)(hp + (size_t)i * HID + lane * 2);
    float ax = self.x, ay = self.y;
    float bx = 0.f, by = 0.f;
    int e = 0;
    for (; e + 1 < m; e += 2) {
        int s0 = csr[start + e];
        int s1 = csr[start + e + 1];
        float2 v0 = *(const float2*)(hp + (size_t)s0 * HID + lane * 2);
        float2 v1 = *(const float2*)(hp + (size_t)s1 * HID + lane * 2);
        ax += v0.x; ay += v0.y;
        bx += v1.x; by += v1.y;
    }
    if (e < m) {
        int s0 = csr[start + e];
        float2 v0 = *(const float2*)(hp + (size_t)s0 * HID + lane * 2);
        ax += v0.x; ay += v0.y;
    }
    float sc = isd[i];
    float rx = fmaxf(fmaf(sc, ax + bx, bias[lane * 2]), 0.f);
    float ry = fmaxf(fmaf(sc, ay + by, bias[lane * 2 + 1]), 0.f);
    *(float2*)(out + (size_t)i * HID + lane * 2) = make_float2(rx, ry);
}

// ---------------- pooling ----------------
__global__ void k_count_nodes(const int* __restrict__ batch, int* counts) {
    int i = blockIdx.x * 256 + threadIdx.x;
    if (i < N_NODES) atomicAdd(&counts[batch[i]], 1);
}

__global__ void k_pool(const float* __restrict__ h, const int* __restrict__ batch,
                       float* sums, float* maxs) {
    int t = threadIdx.x;  // feature
    int n0 = blockIdx.x * 128;
    int nend = min(n0 + 128, N_NODES);
    int cur = batch[n0];
    float s = 0.f, mx = 0.f;  // h >= 0 post-relu, so 0 is a valid max identity
    for (int n = n0; n < nend; n++) {
        int g = batch[n];
        if (g != cur) {
            atomicAdd(&sums[cur * HID + t], s);
            atomicMax((int*)&maxs[cur * HID + t], __float_as_int(mx));
            s = 0.f; mx = 0.f; cur = g;
        }
        float v = h[(size_t)n * HID + t];
        s += v;
        mx = fmaxf(mx, v);
    }
    atomicAdd(&sums[cur * HID + t], s);
    atomicMax((int*)&maxs[cur * HID + t], __float_as_int(mx));
}

// ---------------- head: aggr assembly + logits (FLOAT32 outputs) ----------
__global__ void k_final(const float* __restrict__ sums, const float* __restrict__ maxs,
                        const int* __restrict__ counts, const float* __restrict__ Wa,
                        const float* __restrict__ ba, float* __restrict__ out) {
    __shared__ float a[256];
    __shared__ float red[4];
    int g = blockIdx.x, t = threadIdx.x;
    float denom = fmaxf((float)counts[g], 1.f);
    float val = (t < 128) ? (sums[g * HID + t] / denom) : maxs[g * HID + (t - 128)];
    a[t] = val;
    out[NGRAPH * NCLS + g * 256 + t] = val;   // aggr (output 1), float32
    __syncthreads();
    for (int c = 0; c < NCLS; c++) {
        float p = a[t] * Wa[t * NCLS + c];
        for (int o = 32; o > 0; o >>= 1) p += __shfl_down(p, o);
        if ((t & 63) == 0) red[t >> 6] = p;
        __syncthreads();
        if (t == 0) {
            out[g * NCLS + c] = red[0] + red[1] + red[2] + red[3] + ba[c];  // logits
        }
        __syncthreads();
    }
}

extern "C" void kernel_launch(void* const* d_in, const int* in_sizes, int n_in,
                              void* d_out, int out_size, void* d_ws, size_t ws_size,
                              hipStream_t stream) {
    const float* x = (const float*)d_in[0];
    const int* ei = (const int*)d_in[1];   // (2,E) row-major: src=ei[0:E], dst=ei[E:2E]
    const int* src = ei;
    const int* dst = ei + N_EDGES;
    const int* batch = (const int*)d_in[2];
    const float* W0 = (const float*)d_in[3];
    const float* b0 = (const float*)d_in[4];
    const float* W1 = (const float*)d_in[5];
    const float* b1 = (const float*)d_in[6];
    const float* W2 = (const float*)d_in[7];
    const float* b2 = (const float*)d_in[8];
    const float* Wa = (const float*)d_in[9];
    const float* ba = (const float*)d_in[10];
    float* out = (float*)d_out;            // float32 outputs (R6 diagnosis)

    char* ws = (char*)d_ws;
    float* isd    = (float*)(ws + 0);         // 50000 f32
    int*   cnt    = (int*)(ws + 200192);      // 50000 i32
    int*   rowp   = (int*)(ws + 400384);      // 50000 i32
    int*   nxt    = (int*)(ws + 600576);      // 50000 i32
    int*   bsum   = (int*)(ws + 800768);      // 49 i32
    int*   csr    = (int*)(ws + 801024);      // 800000 i32
    int*   counts = (int*)(ws + 4001024);     // 64 i32
    float* sums   = (float*)(ws + 4001280);   // 8192 f32
    float* maxs   = (float*)(ws + 4034048);   // 8192 f32
    float* h      = (float*)(ws + 4066816);   // 50000x128 f32
    float* hp     = (float*)(ws + 29666816);  // 50000x128 f32
    // total ~55.3 MB

    k_init<<<196, 256, 0, stream>>>(cnt, counts, sums, maxs);
    k_count_edges<<<(N_EDGES + 255) / 256, 256, 0, stream>>>(dst, cnt);
    k_isd<<<(N_NODES + 255) / 256, 256, 0, stream>>>(cnt, isd);
    k_scanA<<<49, 1024, 0, stream>>>(cnt, rowp, bsum);
    k_scanB<<<1, 64, 0, stream>>>(bsum);
    k_scanC<<<(N_NODES + 255) / 256, 256, 0, stream>>>(rowp, bsum, nxt);
    k_fill<<<(N_EDGES + 255) / 256, 256, 0, stream>>>(src, dst, nxt, csr);

    // layer 0 reads x directly (f32); layers 1-2 read h
    k_gemm<<<782, 256, 0, stream>>>(x, W0, isd, hp);
    k_agg<<<12500, 256, 0, stream>>>(hp, csr, rowp, cnt, isd, b0, h);
    k_gemm<<<782, 256, 0, stream>>>(h, W1, isd, hp);
    k_agg<<<12500, 256, 0, stream>>>(hp, csr, rowp, cnt, isd, b1, h);
    k_gemm<<<782, 256, 0, stream>>>(h, W2, isd, hp);
    k_agg<<<12500, 256, 0, stream>>>(hp, csr, rowp, cnt, isd, b2, h);

    k_count_nodes<<<(N_NODES + 255) / 256, 256, 0, stream>>>(batch, counts);
    k_pool<<<391, 128, 0, stream>>>(h, batch, sums, maxs);
    k_final<<<NGRAPH, 256, 0, stream>>>(sums, maxs, counts, Wa, ba, out);
}

// Round 8
// 512.599 us; speedup vs baseline: 1.4436x; 1.4436x over previous
//
#include <hip/hip_runtime.h>
#include <stdint.h>

#define N_NODES 50000
#define N_EDGES 800000
#define FEAT 128
#define HID 128
#define NCLS 10
#define NGRAPH 64

// ---------------- init: zero counters/accumulators (ws is poisoned 0xAA) ---
__global__ void k_init(int* cnt, float* sums, float* maxs) {
    int i = blockIdx.x * 256 + threadIdx.x;
    if (i < N_NODES) cnt[i] = 0;
    if (i < NGRAPH * HID) { sums[i] = 0.f; maxs[i] = 0.f; }
}

// ---------------- degree histogram over dst ----------------
__global__ void k_count_edges(const int* __restrict__ dst, int* cnt) {
    int i = blockIdx.x * 256 + threadIdx.x;
    if (i < N_EDGES) atomicAdd(&cnt[dst[i]], 1);
}

__global__ void k_isd(const int* __restrict__ cnt, float* isd) {
    int i = blockIdx.x * 256 + threadIdx.x;
    if (i < N_NODES) isd[i] = 1.0f / sqrtf((float)cnt[i] + 1.0f);
}

// ---------------- two-level exclusive scan of cnt -> rowp ----------------
__global__ void k_scanA(const int* __restrict__ cnt, int* rowp, int* bsum) {
    __shared__ int s[1024];
    int t = threadIdx.x;
    int i = blockIdx.x * 1024 + t;
    int v = (i < N_NODES) ? cnt[i] : 0;
    s[t] = v;
    __syncthreads();
    for (int o = 1; o < 1024; o <<= 1) {
        int x = (t >= o) ? s[t - o] : 0;
        __syncthreads();
        s[t] += x;
        __syncthreads();
    }
    if (i < N_NODES) rowp[i] = s[t] - v;       // local exclusive
    if (t == 1023) bsum[blockIdx.x] = s[t];    // block total
}

__global__ void k_scanB(int* bsum) {  // 49 block sums -> exclusive offsets
    int t = threadIdx.x;
    int v = (t < 49) ? bsum[t] : 0;
    int orig = v;
    for (int o = 1; o < 64; o <<= 1) {
        int y = __shfl_up(v, o);
        if (t >= o) v += y;
    }
    if (t < 49) bsum[t] = v - orig;
}

__global__ void k_scanC(int* rowp, const int* __restrict__ bsum, int* nxt) {
    int i = blockIdx.x * 256 + threadIdx.x;
    if (i < N_NODES) {
        int r = rowp[i] + bsum[i >> 10];
        rowp[i] = r;
        nxt[i] = r;
    }
}

__global__ void k_fill(const int* __restrict__ src, const int* __restrict__ dst,
                       int* nxt, int* csr) {
    int i = blockIdx.x * 256 + threadIdx.x;
    if (i < N_EDGES) {
        int d = dst[i];
        int p = atomicAdd(&nxt[d], 1);
        csr[p] = src[i];
    }
}

// ---------------- graph boundaries via binary search (batch is SORTED) ----
// Replaces 50k-atomic histogram (was 235 us of same-address serialization).
__global__ void k_bounds(const int* __restrict__ batch, int* bound, int* counts) {
    int g = threadIdx.x;
    if (g <= NGRAPH) {
        int lo = 0, hi = N_NODES;          // lower_bound of g
        while (lo < hi) {
            int mid = (lo + hi) >> 1;
            if (batch[mid] < g) lo = mid + 1; else hi = mid;
        }
        bound[g] = lo;
    }
    __syncthreads();
    if (g < NGRAPH) counts[g] = bound[g + 1] - bound[g];
}

// ---------------- GEMM: O[i][:] = isd[i] * (A[i][:] @ W)  (fp32 vector) ----
__device__ __forceinline__ void fma4(float4& a, float s, const float4& w) {
    a.x = fmaf(s, w.x, a.x); a.y = fmaf(s, w.y, a.y);
    a.z = fmaf(s, w.z, a.z); a.w = fmaf(s, w.w, a.w);
}

__global__ void k_gemm(const float* __restrict__ A, const float* __restrict__ W,
                       const float* __restrict__ isd, float* __restrict__ O) {
    __shared__ float Xs[8][64];
    __shared__ float Ws[8][128];
    int t = threadIdx.x;
    int row0 = blockIdx.x * 64;
    int tr = (t >> 5) << 3;   // 8 rows per thread
    int tc = (t & 31) << 2;   // 4 cols per thread
    float4 acc[8];
#pragma unroll
    for (int j = 0; j < 8; j++) acc[j] = make_float4(0.f, 0.f, 0.f, 0.f);

    for (int k0 = 0; k0 < 128; k0 += 8) {
        int e = t * 2;
        int xr = e >> 3, xk = e & 7;
        int gr = row0 + xr;
        float2 xv = make_float2(0.f, 0.f);
        if (gr < N_NODES) xv = *(const float2*)(A + (size_t)gr * 128 + k0 + xk);
        Xs[xk][xr] = xv.x;
        Xs[xk + 1][xr] = xv.y;
        int we = t * 4;
        int wk = we >> 7, wc = we & 127;
        float4 wv4 = *(const float4*)(W + (size_t)(k0 + wk) * 128 + wc);
        Ws[wk][wc + 0] = wv4.x;
        Ws[wk][wc + 1] = wv4.y;
        Ws[wk][wc + 2] = wv4.z;
        Ws[wk][wc + 3] = wv4.w;
        __syncthreads();
#pragma unroll
        for (int kk = 0; kk < 8; kk++) {
            float4 xa = *(const float4*)&Xs[kk][tr];
            float4 xb = *(const float4*)&Xs[kk][tr + 4];
            float4 wv = *(const float4*)&Ws[kk][tc];
            fma4(acc[0], xa.x, wv); fma4(acc[1], xa.y, wv);
            fma4(acc[2], xa.z, wv); fma4(acc[3], xa.w, wv);
            fma4(acc[4], xb.x, wv); fma4(acc[5], xb.y, wv);
            fma4(acc[6], xb.z, wv); fma4(acc[7], xb.w, wv);
        }
        __syncthreads();
    }
#pragma unroll
    for (int j = 0; j < 8; j++) {
        int r = row0 + tr + j;
        if (r < N_NODES) {
            float sc = isd[r];
            float4 o = acc[j];
            o.x *= sc; o.y *= sc; o.z *= sc; o.w *= sc;
            *(float4*)(O + (size_t)r * 128 + tc) = o;
        }
    }
}

// ---------------- aggregation: h[i] = relu(isd[i]*(sum hp[src] + hp[i]) + b)
__global__ void k_agg(const float* __restrict__ hp, const int* __restrict__ csr,
                      const int* __restrict__ rowp, const int* __restrict__ cnt,
                      const float* __restrict__ isd, const float* __restrict__ bias,
                      float* __restrict__ out) {
    int wid = threadIdx.x >> 6;
    int lane = threadIdx.x & 63;
    int i = blockIdx.x * 4 + wid;
    if (i >= N_NODES) return;
    int start = rowp[i];
    int m = cnt[i];
    float2 self = *(const float2*)(hp + (size_t)i * HID + lane * 2);
    float ax = self.x, ay = self.y;
    float bx = 0.f, by = 0.f;
    int e = 0;
    for (; e + 1 < m; e += 2) {
        int s0 = csr[start + e];
        int s1 = csr[start + e + 1];
        float2 v0 = *(const float2*)(hp + (size_t)s0 * HID + lane * 2);
        float2 v1 = *(const float2*)(hp + (size_t)s1 * HID + lane * 2);
        ax += v0.x; ay += v0.y;
        bx += v1.x; by += v1.y;
    }
    if (e < m) {
        int s0 = csr[start + e];
        float2 v0 = *(const float2*)(hp + (size_t)s0 * HID + lane * 2);
        ax += v0.x; ay += v0.y;
    }
    float sc = isd[i];
    float rx = fmaxf(fmaf(sc, ax + bx, bias[lane * 2]), 0.f);
    float ry = fmaxf(fmaf(sc, ay + by, bias[lane * 2 + 1]), 0.f);
    *(float2*)(out + (size_t)i * HID + lane * 2) = make_float2(rx, ry);
}

// ---------------- pooling ----------------
__global__ void k_pool(const float* __restrict__ h, const int* __restrict__ batch,
                       float* sums, float* maxs) {
    int t = threadIdx.x;  // feature
    int n0 = blockIdx.x * 128;
    int nend = min(n0 + 128, N_NODES);
    int cur = batch[n0];
    float s = 0.f, mx = 0.f;  // h >= 0 post-relu, so 0 is a valid max identity
    for (int n = n0; n < nend; n++) {
        int g = batch[n];
        if (g != cur) {
            atomicAdd(&sums[cur * HID + t], s);
            atomicMax((int*)&maxs[cur * HID + t], __float_as_int(mx));
            s = 0.f; mx = 0.f; cur = g;
        }
        float v = h[(size_t)n * HID + t];
        s += v;
        mx = fmaxf(mx, v);
    }
    atomicAdd(&sums[cur * HID + t], s);
    atomicMax((int*)&maxs[cur * HID + t], __float_as_int(mx));
}

// ---------------- head: aggr assembly + logits (float32 outputs) ----------
__global__ void k_final(const float* __restrict__ sums, const float* __restrict__ maxs,
                        const int* __restrict__ counts, const float* __restrict__ Wa,
                        const float* __restrict__ ba, float* __restrict__ out) {
    __shared__ float a[256];
    __shared__ float red[4];
    int g = blockIdx.x, t = threadIdx.x;
    float denom = fmaxf((float)counts[g], 1.f);
    float val = (t < 128) ? (sums[g * HID + t] / denom) : maxs[g * HID + (t - 128)];
    a[t] = val;
    out[NGRAPH * NCLS + g * 256 + t] = val;   // aggr (output 1)
    __syncthreads();
    for (int c = 0; c < NCLS; c++) {
        float p = a[t] * Wa[t * NCLS + c];
        for (int o = 32; o > 0; o >>= 1) p += __shfl_down(p, o);
        if ((t & 63) == 0) red[t >> 6] = p;
        __syncthreads();
        if (t == 0) {
            out[g * NCLS + c] = red[0] + red[1] + red[2] + red[3] + ba[c];  // logits
        }
        __syncthreads();
    }
}

extern "C" void kernel_launch(void* const* d_in, const int* in_sizes, int n_in,
                              void* d_out, int out_size, void* d_ws, size_t ws_size,
                              hipStream_t stream) {
    const float* x = (const float*)d_in[0];
    const int* ei = (const int*)d_in[1];   // (2,E) row-major: src=ei[0:E], dst=ei[E:2E]
    const int* src = ei;
    const int* dst = ei + N_EDGES;
    const int* batch = (const int*)d_in[2];
    const float* W0 = (const float*)d_in[3];
    const float* b0 = (const float*)d_in[4];
    const float* W1 = (const float*)d_in[5];
    const float* b1 = (const float*)d_in[6];
    const float* W2 = (const float*)d_in[7];
    const float* b2 = (const float*)d_in[8];
    const float* Wa = (const float*)d_in[9];
    const float* ba = (const float*)d_in[10];
    float* out = (float*)d_out;            // float32 outputs

    char* ws = (char*)d_ws;
    float* isd    = (float*)(ws + 0);         // 50000 f32
    int*   cnt    = (int*)(ws + 200192);      // 50000 i32
    int*   rowp   = (int*)(ws + 400384);      // 50000 i32
    int*   nxt    = (int*)(ws + 600576);      // 50000 i32
    int*   bsum   = (int*)(ws + 800768);      // 49 i32
    int*   bound  = (int*)(ws + 800968);      // 65 i32
    int*   csr    = (int*)(ws + 801280);      // 800000 i32
    int*   counts = (int*)(ws + 4001280);     // 64 i32
    float* sums   = (float*)(ws + 4001536);   // 8192 f32
    float* maxs   = (float*)(ws + 4034304);   // 8192 f32
    float* h      = (float*)(ws + 4067072);   // 50000x128 f32
    float* hp     = (float*)(ws + 29667072);  // 50000x128 f32
    // total ~55.3 MB

    k_init<<<196, 256, 0, stream>>>(cnt, sums, maxs);
    k_count_edges<<<(N_EDGES + 255) / 256, 256, 0, stream>>>(dst, cnt);
    k_isd<<<(N_NODES + 255) / 256, 256, 0, stream>>>(cnt, isd);
    k_scanA<<<49, 1024, 0, stream>>>(cnt, rowp, bsum);
    k_scanB<<<1, 64, 0, stream>>>(bsum);
    k_scanC<<<(N_NODES + 255) / 256, 256, 0, stream>>>(rowp, bsum, nxt);
    k_fill<<<(N_EDGES + 255) / 256, 256, 0, stream>>>(src, dst, nxt, csr);
    k_bounds<<<1, 128, 0, stream>>>(batch, bound, counts);

    // layer 0 reads x directly (f32); layers 1-2 read h
    k_gemm<<<782, 256, 0, stream>>>(x, W0, isd, hp);
    k_agg<<<12500, 256, 0, stream>>>(hp, csr, rowp, cnt, isd, b0, h);
    k_gemm<<<782, 256, 0, stream>>>(h, W1, isd, hp);
    k_agg<<<12500, 256, 0, stream>>>(hp, csr, rowp, cnt, isd, b1, h);
    k_gemm<<<782, 256, 0, stream>>>(h, W2, isd, hp);
    k_agg<<<12500, 256, 0, stream>>>(hp, csr, rowp, cnt, isd, b2, h);

    k_pool<<<391, 128, 0, stream>>>(h, batch, sums, maxs);
    k_final<<<NGRAPH, 256, 0, stream>>>(sums, maxs, counts, Wa, ba, out);
}

// Round 9
// 497.076 us; speedup vs baseline: 1.4887x; 1.0312x over previous
//
#include <hip/hip_runtime.h>
#include <stdint.h>

#define N_NODES 50000
#define N_EDGES 800000
#define FEAT 128
#define HID 128
#define NCLS 10
#define NGRAPH 64

// ---------------- init: zero counters/accumulators (ws is poisoned 0xAA) ---
__global__ void k_init(int* cnt, float* sums, float* maxs) {
    int i = blockIdx.x * 256 + threadIdx.x;
    if (i < N_NODES) cnt[i] = 0;
    if (i < NGRAPH * HID) { sums[i] = 0.f; maxs[i] = 0.f; }
}

// ---------------- degree histogram over dst ----------------
__global__ void k_count_edges(const int* __restrict__ dst, int* cnt) {
    int i = blockIdx.x * 256 + threadIdx.x;
    if (i < N_EDGES) atomicAdd(&cnt[dst[i]], 1);
}

// ---------------- two-level exclusive scan of cnt -> rowp ----------------
__global__ void k_scanA(const int* __restrict__ cnt, int* rowp, int* bsum) {
    __shared__ int s[1024];
    int t = threadIdx.x;
    int i = blockIdx.x * 1024 + t;
    int v = (i < N_NODES) ? cnt[i] : 0;
    s[t] = v;
    __syncthreads();
    for (int o = 1; o < 1024; o <<= 1) {
        int x = (t >= o) ? s[t - o] : 0;
        __syncthreads();
        s[t] += x;
        __syncthreads();
    }
    if (i < N_NODES) rowp[i] = s[t] - v;       // local exclusive
    if (t == 1023) bsum[blockIdx.x] = s[t];    // block total
}

__global__ void k_scanB(int* bsum) {  // 49 block sums -> exclusive offsets
    int t = threadIdx.x;
    int v = (t < 49) ? bsum[t] : 0;
    int orig = v;
    for (int o = 1; o < 64; o <<= 1) {
        int y = __shfl_up(v, o);
        if (t >= o) v += y;
    }
    if (t < 49) bsum[t] = v - orig;
}

// scanC + isd fused (both elementwise over nodes)
__global__ void k_scanC(int* rowp, const int* __restrict__ bsum, int* nxt,
                        const int* __restrict__ cnt, float* isd) {
    int i = blockIdx.x * 256 + threadIdx.x;
    if (i < N_NODES) {
        int r = rowp[i] + bsum[i >> 10];
        rowp[i] = r;
        nxt[i] = r;
        isd[i] = 1.0f / sqrtf((float)cnt[i] + 1.0f);
    }
}

__global__ void k_fill(const int* __restrict__ src, const int* __restrict__ dst,
                       int* nxt, int* csr) {
    int i = blockIdx.x * 256 + threadIdx.x;
    if (i < N_EDGES) {
        int d = dst[i];
        int p = atomicAdd(&nxt[d], 1);
        csr[p] = src[i];
    }
}

// ---------------- graph boundaries via binary search (batch is SORTED) ----
__global__ void k_bounds(const int* __restrict__ batch, int* bound, int* counts) {
    int g = threadIdx.x;
    if (g <= NGRAPH) {
        int lo = 0, hi = N_NODES;          // lower_bound of g
        while (lo < hi) {
            int mid = (lo + hi) >> 1;
            if (batch[mid] < g) lo = mid + 1; else hi = mid;
        }
        bound[g] = lo;
    }
    __syncthreads();
    if (g < NGRAPH) counts[g] = bound[g + 1] - bound[g];
}

// ---------------- GEMM: O[i][:] = isd[i] * (A[i][:] @ W)  (fp32 vector) ----
__device__ __forceinline__ void fma4(float4& a, float s, const float4& w) {
    a.x = fmaf(s, w.x, a.x); a.y = fmaf(s, w.y, a.y);
    a.z = fmaf(s, w.z, a.z); a.w = fmaf(s, w.w, a.w);
}

__global__ void k_gemm(const float* __restrict__ A, const float* __restrict__ W,
                       const float* __restrict__ isd, float* __restrict__ O) {
    __shared__ float Xs[8][64];
    __shared__ float Ws[8][128];
    int t = threadIdx.x;
    int row0 = blockIdx.x * 64;
    int tr = (t >> 5) << 3;   // 8 rows per thread
    int tc = (t & 31) << 2;   // 4 cols per thread
    float4 acc[8];
#pragma unroll
    for (int j = 0; j < 8; j++) acc[j] = make_float4(0.f, 0.f, 0.f, 0.f);

    for (int k0 = 0; k0 < 128; k0 += 8) {
        int e = t * 2;
        int xr = e >> 3, xk = e & 7;
        int gr = row0 + xr;
        float2 xv = make_float2(0.f, 0.f);
        if (gr < N_NODES) xv = *(const float2*)(A + (size_t)gr * 128 + k0 + xk);
        Xs[xk][xr] = xv.x;
        Xs[xk + 1][xr] = xv.y;
        int we = t * 4;
        int wk = we >> 7, wc = we & 127;
        float4 wv4 = *(const float4*)(W + (size_t)(k0 + wk) * 128 + wc);
        Ws[wk][wc + 0] = wv4.x;
        Ws[wk][wc + 1] = wv4.y;
        Ws[wk][wc + 2] = wv4.z;
        Ws[wk][wc + 3] = wv4.w;
        __syncthreads();
#pragma unroll
        for (int kk = 0; kk < 8; kk++) {
            float4 xa = *(const float4*)&Xs[kk][tr];
            float4 xb = *(const float4*)&Xs[kk][tr + 4];
            float4 wv = *(const float4*)&Ws[kk][tc];
            fma4(acc[0], xa.x, wv); fma4(acc[1], xa.y, wv);
            fma4(acc[2], xa.z, wv); fma4(acc[3], xa.w, wv);
            fma4(acc[4], xb.x, wv); fma4(acc[5], xb.y, wv);
            fma4(acc[6], xb.z, wv); fma4(acc[7], xb.w, wv);
        }
        __syncthreads();
    }
#pragma unroll
    for (int j = 0; j < 8; j++) {
        int r = row0 + tr + j;
        if (r < N_NODES) {
            float sc = isd[r];
            float4 o = acc[j];
            o.x *= sc; o.y *= sc; o.z *= sc; o.w *= sc;
            *(float4*)(O + (size_t)r * 128 + tc) = o;
        }
    }
}

// ---------------- aggregation: h[i] = relu(isd[i]*(sum hp[src] + hp[i]) + b)
// One wave per node. R9: 4-way unrolled gather for memory-level parallelism
// (was 2 outstanding row-gathers per wave -> latency-bound at 2.9 TB/s).
__global__ void k_agg(const float* __restrict__ hp, const int* __restrict__ csr,
                      const int* __restrict__ rowp, const int* __restrict__ cnt,
                      const float* __restrict__ isd, const float* __restrict__ bias,
                      float* __restrict__ out) {
    int wid = threadIdx.x >> 6;
    int lane = threadIdx.x & 63;
    int i = blockIdx.x * 4 + wid;
    if (i >= N_NODES) return;
    int start = rowp[i];
    int m = cnt[i];
    float2 self = *(const float2*)(hp + (size_t)i * HID + lane * 2);
    float a0x = self.x, a0y = self.y;
    float a1x = 0.f, a1y = 0.f;
    float a2x = 0.f, a2y = 0.f;
    float a3x = 0.f, a3y = 0.f;
    int e = 0;
    for (; e + 3 < m; e += 4) {
        int s0 = csr[start + e];
        int s1 = csr[start + e + 1];
        int s2 = csr[start + e + 2];
        int s3 = csr[start + e + 3];
        float2 v0 = *(const float2*)(hp + (size_t)s0 * HID + lane * 2);
        float2 v1 = *(const float2*)(hp + (size_t)s1 * HID + lane * 2);
        float2 v2 = *(const float2*)(hp + (size_t)s2 * HID + lane * 2);
        float2 v3 = *(const float2*)(hp + (size_t)s3 * HID + lane * 2);
        a0x += v0.x; a0y += v0.y;
        a1x += v1.x; a1y += v1.y;
        a2x += v2.x; a2y += v2.y;
        a3x += v3.x; a3y += v3.y;
    }
    if (e + 1 < m) {
        int s0 = csr[start + e];
        int s1 = csr[start + e + 1];
        float2 v0 = *(const float2*)(hp + (size_t)s0 * HID + lane * 2);
        float2 v1 = *(const float2*)(hp + (size_t)s1 * HID + lane * 2);
        a0x += v0.x; a0y += v0.y;
        a1x += v1.x; a1y += v1.y;
        e += 2;
    }
    if (e < m) {
        int s0 = csr[start + e];
        float2 v0 = *(const float2*)(hp + (size_t)s0 * HID + lane * 2);
        a2x += v0.x; a2y += v0.y;
    }
    float sx = (a0x + a1x) + (a2x + a3x);
    float sy = (a0y + a1y) + (a2y + a3y);
    float sc = isd[i];
    float rx = fmaxf(fmaf(sc, sx, bias[lane * 2]), 0.f);
    float ry = fmaxf(fmaf(sc, sy, bias[lane * 2 + 1]), 0.f);
    *(float2*)(out + (size_t)i * HID + lane * 2) = make_float2(rx, ry);
}

// ---------------- pooling ----------------
__global__ void k_pool(const float* __restrict__ h, const int* __restrict__ batch,
                       float* sums, float* maxs) {
    int t = threadIdx.x;  // feature
    int n0 = blockIdx.x * 128;
    int nend = min(n0 + 128, N_NODES);
    int cur = batch[n0];
    float s = 0.f, mx = 0.f;  // h >= 0 post-relu, so 0 is a valid max identity
    for (int n = n0; n < nend; n++) {
        int g = batch[n];
        if (g != cur) {
            atomicAdd(&sums[cur * HID + t], s);
            atomicMax((int*)&maxs[cur * HID + t], __float_as_int(mx));
            s = 0.f; mx = 0.f; cur = g;
        }
        float v = h[(size_t)n * HID + t];
        s += v;
        mx = fmaxf(mx, v);
    }
    atomicAdd(&sums[cur * HID + t], s);
    atomicMax((int*)&maxs[cur * HID + t], __float_as_int(mx));
}

// ---------------- head: aggr assembly + logits (float32 outputs) ----------
__global__ void k_final(const float* __restrict__ sums, const float* __restrict__ maxs,
                        const int* __restrict__ counts, const float* __restrict__ Wa,
                        const float* __restrict__ ba, float* __restrict__ out) {
    __shared__ float a[256];
    __shared__ float red[4];
    int g = blockIdx.x, t = threadIdx.x;
    float denom = fmaxf((float)counts[g], 1.f);
    float val = (t < 128) ? (sums[g * HID + t] / denom) : maxs[g * HID + (t - 128)];
    a[t] = val;
    out[NGRAPH * NCLS + g * 256 + t] = val;   // aggr (output 1)
    __syncthreads();
    for (int c = 0; c < NCLS; c++) {
        float p = a[t] * Wa[t * NCLS + c];
        for (int o = 32; o > 0; o >>= 1) p += __shfl_down(p, o);
        if ((t & 63) == 0) red[t >> 6] = p;
        __syncthreads();
        if (t == 0) {
            out[g * NCLS + c] = red[0] + red[1] + red[2] + red[3] + ba[c];  // logits
        }
        __syncthreads();
    }
}

extern "C" void kernel_launch(void* const* d_in, const int* in_sizes, int n_in,
                              void* d_out, int out_size, void* d_ws, size_t ws_size,
                              hipStream_t stream) {
    const float* x = (const float*)d_in[0];
    const int* ei = (const int*)d_in[1];   // (2,E) row-major: src=ei[0:E], dst=ei[E:2E]
    const int* src = ei;
    const int* dst = ei + N_EDGES;
    const int* batch = (const int*)d_in[2];
    const float* W0 = (const float*)d_in[3];
    const float* b0 = (const float*)d_in[4];
    const float* W1 = (const float*)d_in[5];
    const float* b1 = (const float*)d_in[6];
    const float* W2 = (const float*)d_in[7];
    const float* b2 = (const float*)d_in[8];
    const float* Wa = (const float*)d_in[9];
    const float* ba = (const float*)d_in[10];
    float* out = (float*)d_out;            // float32 outputs

    char* ws = (char*)d_ws;
    float* isd    = (float*)(ws + 0);         // 50000 f32
    int*   cnt    = (int*)(ws + 200192);      // 50000 i32
    int*   rowp   = (int*)(ws + 400384);      // 50000 i32
    int*   nxt    = (int*)(ws + 600576);      // 50000 i32
    int*   bsum   = (int*)(ws + 800768);      // 49 i32
    int*   bound  = (int*)(ws + 800968);      // 65 i32
    int*   csr    = (int*)(ws + 801280);      // 800000 i32
    int*   counts = (int*)(ws + 4001280);     // 64 i32
    float* sums   = (float*)(ws + 4001536);   // 8192 f32
    float* maxs   = (float*)(ws + 4034304);   // 8192 f32
    float* h      = (float*)(ws + 4067072);   // 50000x128 f32
    float* hp     = (float*)(ws + 29667072);  // 50000x128 f32
    // total ~55.3 MB

    k_init<<<196, 256, 0, stream>>>(cnt, sums, maxs);
    k_count_edges<<<(N_EDGES + 255) / 256, 256, 0, stream>>>(dst, cnt);
    k_scanA<<<49, 1024, 0, stream>>>(cnt, rowp, bsum);
    k_scanB<<<1, 64, 0, stream>>>(bsum);
    k_scanC<<<(N_NODES + 255) / 256, 256, 0, stream>>>(rowp, bsum, nxt, cnt, isd);
    k_fill<<<(N_EDGES + 255) / 256, 256, 0, stream>>>(src, dst, nxt, csr);
    k_bounds<<<1, 128, 0, stream>>>(batch, bound, counts);

    // layer 0 reads x directly (f32); layers 1-2 read h
    k_gemm<<<782, 256, 0, stream>>>(x, W0, isd, hp);
    k_agg<<<12500, 256, 0, stream>>>(hp, csr, rowp, cnt, isd, b0, h);
    k_gemm<<<782, 256, 0, stream>>>(h, W1, isd, hp);
    k_agg<<<12500, 256, 0, stream>>>(hp, csr, rowp, cnt, isd, b1, h);
    k_gemm<<<782, 256, 0, stream>>>(h, W2, isd, hp);
    k_agg<<<12500, 256, 0, stream>>>(hp, csr, rowp, cnt, isd, b2, h);

    k_pool<<<391, 128, 0, stream>>>(h, batch, sums, maxs);
    k_final<<<NGRAPH, 256, 0, stream>>>(sums, maxs, counts, Wa, ba, out);
}

// Round 10
// 463.392 us; speedup vs baseline: 1.5969x; 1.0727x over previous
//
#include <hip/hip_runtime.h>
#include <stdint.h>

#define N_NODES 50000
#define N_EDGES 800000
#define FEAT 128
#define HID 128
#define NCLS 10
#define NGRAPH 64

typedef unsigned short ushort_t;
typedef __attribute__((ext_vector_type(8))) short bf16x8;
typedef __attribute__((ext_vector_type(4))) float f32x4;

__device__ __forceinline__ ushort_t f2bf(float f) {
    union { float f; unsigned int i; } v; v.f = f;
    unsigned int u = v.i;
    return (ushort_t)((u + 0x7FFFu + ((u >> 16) & 1u)) >> 16);
}
__device__ __forceinline__ float bf2f(ushort_t u) {
    union { unsigned int i; float f; } v; v.i = ((unsigned int)u) << 16; return v.f;
}

// ---------------- init ----------------
__global__ void k_init(int* cnt, float* sums, float* maxs) {
    int i = blockIdx.x * 256 + threadIdx.x;
    if (i < N_NODES) cnt[i] = 0;
    if (i < NGRAPH * HID) { sums[i] = 0.f; maxs[i] = 0.f; }
}

__global__ void k_count_edges(const int* __restrict__ dst, int* cnt) {
    int i = blockIdx.x * 256 + threadIdx.x;
    if (i < N_EDGES) atomicAdd(&cnt[dst[i]], 1);
}

__global__ void k_scanA(const int* __restrict__ cnt, int* rowp, int* bsum) {
    __shared__ int s[1024];
    int t = threadIdx.x;
    int i = blockIdx.x * 1024 + t;
    int v = (i < N_NODES) ? cnt[i] : 0;
    s[t] = v;
    __syncthreads();
    for (int o = 1; o < 1024; o <<= 1) {
        int x = (t >= o) ? s[t - o] : 0;
        __syncthreads();
        s[t] += x;
        __syncthreads();
    }
    if (i < N_NODES) rowp[i] = s[t] - v;
    if (t == 1023) bsum[blockIdx.x] = s[t];
}

__global__ void k_scanB(int* bsum) {
    int t = threadIdx.x;
    int v = (t < 49) ? bsum[t] : 0;
    int orig = v;
    for (int o = 1; o < 64; o <<= 1) {
        int y = __shfl_up(v, o);
        if (t >= o) v += y;
    }
    if (t < 49) bsum[t] = v - orig;
}

__global__ void k_scanC(int* rowp, const int* __restrict__ bsum, int* nxt,
                        const int* __restrict__ cnt, float* isd) {
    int i = blockIdx.x * 256 + threadIdx.x;
    if (i < N_NODES) {
        int r = rowp[i] + bsum[i >> 10];
        rowp[i] = r;
        nxt[i] = r;
        isd[i] = 1.0f / sqrtf((float)cnt[i] + 1.0f);
    }
}

__global__ void k_fill(const int* __restrict__ src, const int* __restrict__ dst,
                       int* nxt, int* csr) {
    int i = blockIdx.x * 256 + threadIdx.x;
    if (i < N_EDGES) {
        int d = dst[i];
        int p = atomicAdd(&nxt[d], 1);
        csr[p] = src[i];
    }
}

__global__ void k_bounds(const int* __restrict__ batch, int* bound, int* counts) {
    int g = threadIdx.x;
    if (g <= NGRAPH) {
        int lo = 0, hi = N_NODES;
        while (lo < hi) {
            int mid = (lo + hi) >> 1;
            if (batch[mid] < g) lo = mid + 1; else hi = mid;
        }
        bound[g] = lo;
    }
    __syncthreads();
    if (g < NGRAPH) counts[g] = bound[g + 1] - bound[g];
}

// ---------------- W split+pack into MFMA B-fragment order ----------------
// packed index for (kk, c, lane, j): ((kk*8+c)*64 + lane)*8 + j
// holds W[32*kk + (lane>>4)*8 + j][16*c + (lane&15)]
__global__ void k_wsplit(const float* __restrict__ W0, const float* __restrict__ W1,
                         const float* __restrict__ W2, ushort_t* Whi, ushort_t* Wlo) {
    int gid = blockIdx.x * 256 + threadIdx.x;      // 3*32*512 = 49152 items
    if (gid >= 3 * 32 * 512) return;
    int l = gid / (32 * 512);
    int rem = gid - l * 32 * 512;
    int tile = rem >> 9;          // kk*8+c
    int p = rem & 511;            // lane*8+j
    int lane = p >> 3, j = p & 7;
    int kk = tile >> 3, c = tile & 7;
    int k = 32 * kk + (lane >> 4) * 8 + j;
    int n = 16 * c + (lane & 15);
    const float* W = (l == 0) ? W0 : (l == 1) ? W1 : W2;
    float x = W[k * 128 + n];
    ushort_t hi = f2bf(x);
    ushort_t lo = f2bf(x - bf2f(hi));
    Whi[l * 16384 + rem] = hi;
    Wlo[l * 16384 + rem] = lo;
}

// ---------------- MFMA GEMM: O[i][:] = isd[i] * (A[i][:] @ W) -------------
// split-bf16: D = Ahi*Bhi + Alo*Bhi + Ahi*Blo  (rel err ~2^-17)
// 64 rows/block, 4 waves, each wave a 16-row stripe x 128 cols. No LDS.
__global__ void k_gemm_mfma(const float* __restrict__ A,
                            const ushort_t* __restrict__ Whi,
                            const ushort_t* __restrict__ Wlo,
                            const float* __restrict__ isd,
                            float* __restrict__ O) {
    int t = threadIdx.x;
    int wv = t >> 6, lane = t & 63;
    int m = lane & 15, q = lane >> 4;
    int row = blockIdx.x * 64 + wv * 16 + m;   // row this lane's A-frag covers
    f32x4 acc[8];
#pragma unroll
    for (int c = 0; c < 8; c++) acc[c] = (f32x4){0.f, 0.f, 0.f, 0.f};

#pragma unroll
    for (int kk = 0; kk < 4; kk++) {
        float4 a0 = make_float4(0.f, 0.f, 0.f, 0.f);
        float4 a1 = make_float4(0.f, 0.f, 0.f, 0.f);
        if (row < N_NODES) {
            const float* ap = A + (size_t)row * 128 + kk * 32 + q * 8;
            a0 = *(const float4*)ap;
            a1 = *(const float4*)(ap + 4);
        }
        float av[8] = {a0.x, a0.y, a0.z, a0.w, a1.x, a1.y, a1.z, a1.w};
        bf16x8 ahi, alo;
#pragma unroll
        for (int j = 0; j < 8; j++) {
            ushort_t h = f2bf(av[j]);
            ahi[j] = (short)h;
            alo[j] = (short)f2bf(av[j] - bf2f(h));
        }
#pragma unroll
        for (int c = 0; c < 8; c++) {
            const bf16x8 bhi = *(const bf16x8*)(Whi + (((kk * 8 + c) * 64 + lane) << 3));
            const bf16x8 blo = *(const bf16x8*)(Wlo + (((kk * 8 + c) * 64 + lane) << 3));
            acc[c] = __builtin_amdgcn_mfma_f32_16x16x32_bf16(ahi, bhi, acc[c], 0, 0, 0);
            acc[c] = __builtin_amdgcn_mfma_f32_16x16x32_bf16(alo, bhi, acc[c], 0, 0, 0);
            acc[c] = __builtin_amdgcn_mfma_f32_16x16x32_bf16(ahi, blo, acc[c], 0, 0, 0);
        }
    }
    // epilogue: C/D layout col=lane&15, row=q*4+reg
    int rb = blockIdx.x * 64 + wv * 16 + q * 4;
    float sc[4];
#pragma unroll
    for (int r = 0; r < 4; r++) sc[r] = (rb + r < N_NODES) ? isd[rb + r] : 0.f;
#pragma unroll
    for (int c = 0; c < 8; c++) {
#pragma unroll
        for (int r = 0; r < 4; r++) {
            int gr = rb + r;
            if (gr < N_NODES) O[(size_t)gr * 128 + c * 16 + m] = acc[c][r] * sc[r];
        }
    }
}

// ---------------- aggregation (R9 4-way MLP version, unchanged) -----------
__global__ void k_agg(const float* __restrict__ hp, const int* __restrict__ csr,
                      const int* __restrict__ rowp, const int* __restrict__ cnt,
                      const float* __restrict__ isd, const float* __restrict__ bias,
                      float* __restrict__ out) {
    int wid = threadIdx.x >> 6;
    int lane = threadIdx.x & 63;
    int i = blockIdx.x * 4 + wid;
    if (i >= N_NODES) return;
    int start = rowp[i];
    int m = cnt[i];
    float2 self = *(const float2*)(hp + (size_t)i * HID + lane * 2);
    float a0x = self.x, a0y = self.y;
    float a1x = 0.f, a1y = 0.f;
    float a2x = 0.f, a2y = 0.f;
    float a3x = 0.f, a3y = 0.f;
    int e = 0;
    for (; e + 3 < m; e += 4) {
        int s0 = csr[start + e];
        int s1 = csr[start + e + 1];
        int s2 = csr[start + e + 2];
        int s3 = csr[start + e + 3];
        float2 v0 = *(const float2*)(hp + (size_t)s0 * HID + lane * 2);
        float2 v1 = *(const float2*)(hp + (size_t)s1 * HID + lane * 2);
        float2 v2 = *(const float2*)(hp + (size_t)s2 * HID + lane * 2);
        float2 v3 = *(const float2*)(hp + (size_t)s3 * HID + lane * 2);
        a0x += v0.x; a0y += v0.y;
        a1x += v1.x; a1y += v1.y;
        a2x += v2.x; a2y += v2.y;
        a3x += v3.x; a3y += v3.y;
    }
    if (e + 1 < m) {
        int s0 = csr[start + e];
        int s1 = csr[start + e + 1];
        float2 v0 = *(const float2*)(hp + (size_t)s0 * HID + lane * 2);
        float2 v1 = *(const float2*)(hp + (size_t)s1 * HID + lane * 2);
        a0x += v0.x; a0y += v0.y;
        a1x += v1.x; a1y += v1.y;
        e += 2;
    }
    if (e < m) {
        int s0 = csr[start + e];
        float2 v0 = *(const float2*)(hp + (size_t)s0 * HID + lane * 2);
        a2x += v0.x; a2y += v0.y;
    }
    float sx = (a0x + a1x) + (a2x + a3x);
    float sy = (a0y + a1y) + (a2y + a3y);
    float sc = isd[i];
    float rx = fmaxf(fmaf(sc, sx, bias[lane * 2]), 0.f);
    float ry = fmaxf(fmaf(sc, sy, bias[lane * 2 + 1]), 0.f);
    *(float2*)(out + (size_t)i * HID + lane * 2) = make_float2(rx, ry);
}

// ---------------- pooling ----------------
__global__ void k_pool(const float* __restrict__ h, const int* __restrict__ batch,
                       float* sums, float* maxs) {
    int t = threadIdx.x;
    int n0 = blockIdx.x * 128;
    int nend = min(n0 + 128, N_NODES);
    int cur = batch[n0];
    float s = 0.f, mx = 0.f;
    for (int n = n0; n < nend; n++) {
        int g = batch[n];
        if (g != cur) {
            atomicAdd(&sums[cur * HID + t], s);
            atomicMax((int*)&maxs[cur * HID + t], __float_as_int(mx));
            s = 0.f; mx = 0.f; cur = g;
        }
        float v = h[(size_t)n * HID + t];
        s += v;
        mx = fmaxf(mx, v);
    }
    atomicAdd(&sums[cur * HID + t], s);
    atomicMax((int*)&maxs[cur * HID + t], __float_as_int(mx));
}

// ---------------- head ----------------
__global__ void k_final(const float* __restrict__ sums, const float* __restrict__ maxs,
                        const int* __restrict__ counts, const float* __restrict__ Wa,
                        const float* __restrict__ ba, float* __restrict__ out) {
    __shared__ float a[256];
    __shared__ float red[4];
    int g = blockIdx.x, t = threadIdx.x;
    float denom = fmaxf((float)counts[g], 1.f);
    float val = (t < 128) ? (sums[g * HID + t] / denom) : maxs[g * HID + (t - 128)];
    a[t] = val;
    out[NGRAPH * NCLS + g * 256 + t] = val;
    __syncthreads();
    for (int c = 0; c < NCLS; c++) {
        float p = a[t] * Wa[t * NCLS + c];
        for (int o = 32; o > 0; o >>= 1) p += __shfl_down(p, o);
        if ((t & 63) == 0) red[t >> 6] = p;
        __syncthreads();
        if (t == 0) {
            out[g * NCLS + c] = red[0] + red[1] + red[2] + red[3] + ba[c];
        }
        __syncthreads();
    }
}

extern "C" void kernel_launch(void* const* d_in, const int* in_sizes, int n_in,
                              void* d_out, int out_size, void* d_ws, size_t ws_size,
                              hipStream_t stream) {
    const float* x = (const float*)d_in[0];
    const int* ei = (const int*)d_in[1];
    const int* src = ei;
    const int* dst = ei + N_EDGES;
    const int* batch = (const int*)d_in[2];
    const float* W0 = (const float*)d_in[3];
    const float* b0 = (const float*)d_in[4];
    const float* W1 = (const float*)d_in[5];
    const float* b1 = (const float*)d_in[6];
    const float* W2 = (const float*)d_in[7];
    const float* b2 = (const float*)d_in[8];
    const float* Wa = (const float*)d_in[9];
    const float* ba = (const float*)d_in[10];
    float* out = (float*)d_out;

    char* ws = (char*)d_ws;
    float*    isd    = (float*)(ws + 0);         // 50000 f32
    int*      cnt    = (int*)(ws + 200192);      // 50000 i32
    int*      rowp   = (int*)(ws + 400384);      // 50000 i32
    int*      nxt    = (int*)(ws + 600576);      // 50000 i32
    int*      bsum   = (int*)(ws + 800768);      // 49 i32
    int*      bound  = (int*)(ws + 800968);      // 65 i32
    int*      csr    = (int*)(ws + 801280);      // 800000 i32
    int*      counts = (int*)(ws + 4001280);     // 64 i32
    float*    sums   = (float*)(ws + 4001536);   // 8192 f32
    float*    maxs   = (float*)(ws + 4034304);   // 8192 f32
    float*    h      = (float*)(ws + 4067072);   // 50000x128 f32
    float*    hp     = (float*)(ws + 29667072);  // 50000x128 f32
    ushort_t* Whi    = (ushort_t*)(ws + 55267072); // 3*16384 bf16 (96 KB)
    ushort_t* Wlo    = (ushort_t*)(ws + 55365376); // 3*16384 bf16 (96 KB)
    // total ~55.5 MB

    k_init<<<196, 256, 0, stream>>>(cnt, sums, maxs);
    k_count_edges<<<(N_EDGES + 255) / 256, 256, 0, stream>>>(dst, cnt);
    k_scanA<<<49, 1024, 0, stream>>>(cnt, rowp, bsum);
    k_scanB<<<1, 64, 0, stream>>>(bsum);
    k_scanC<<<(N_NODES + 255) / 256, 256, 0, stream>>>(rowp, bsum, nxt, cnt, isd);
    k_fill<<<(N_EDGES + 255) / 256, 256, 0, stream>>>(src, dst, nxt, csr);
    k_bounds<<<1, 128, 0, stream>>>(batch, bound, counts);
    k_wsplit<<<192, 256, 0, stream>>>(W0, W1, W2, Whi, Wlo);

    k_gemm_mfma<<<782, 256, 0, stream>>>(x, Whi, Wlo, isd, hp);
    k_agg<<<12500, 256, 0, stream>>>(hp, csr, rowp, cnt, isd, b0, h);
    k_gemm_mfma<<<782, 256, 0, stream>>>(h, Whi + 16384, Wlo + 16384, isd, hp);
    k_agg<<<12500, 256, 0, stream>>>(hp, csr, rowp, cnt, isd, b1, h);
    k_gemm_mfma<<<782, 256, 0, stream>>>(h, Whi + 32768, Wlo + 32768, isd, hp);
    k_agg<<<12500, 256, 0, stream>>>(hp, csr, rowp, cnt, isd, b2, h);

    k_pool<<<391, 128, 0, stream>>>(h, batch, sums, maxs);
    k_final<<<NGRAPH, 256, 0, stream>>>(sums, maxs, counts, Wa, ba, out);
}

// Round 11
// 425.779 us; speedup vs baseline: 1.7379x; 1.0883x over previous
//
#include <hip/hip_runtime.h>
#include <stdint.h>

#define N_NODES 50000
#define N_EDGES 800000
#define FEAT 128
#define HID 128
#define NCLS 10
#define NGRAPH 64

typedef unsigned short ushort_t;
typedef __attribute__((ext_vector_type(8))) short bf16x8;
typedef __attribute__((ext_vector_type(4))) float f32x4;

__device__ __forceinline__ ushort_t f2bf(float f) {
    union { float f; unsigned int i; } v; v.f = f;
    unsigned int u = v.i;
    return (ushort_t)((u + 0x7FFFu + ((u >> 16) & 1u)) >> 16);
}
__device__ __forceinline__ float bf2f(ushort_t u) {
    union { unsigned int i; float f; } v; v.i = ((unsigned int)u) << 16; return v.f;
}

__global__ void k_count_edges(const int* __restrict__ dst, int* cnt) {
    int i = blockIdx.x * 256 + threadIdx.x;
    if (i < N_EDGES) atomicAdd(&cnt[dst[i]], 1);
}

__global__ void k_scanA(const int* __restrict__ cnt, int* rowp, int* bsum) {
    __shared__ int s[1024];
    int t = threadIdx.x;
    int i = blockIdx.x * 1024 + t;
    int v = (i < N_NODES) ? cnt[i] : 0;
    s[t] = v;
    __syncthreads();
    for (int o = 1; o < 1024; o <<= 1) {
        int x = (t >= o) ? s[t - o] : 0;
        __syncthreads();
        s[t] += x;
        __syncthreads();
    }
    if (i < N_NODES) rowp[i] = s[t] - v;
    if (t == 1023) bsum[blockIdx.x] = s[t];
}

// fused: scanC (blocks 0..195) + bounds (block 196) + W split-pack (197..388)
__global__ void k_post(int* rowp, const int* __restrict__ bsum, int* nxt,
                       const int* __restrict__ cnt, float* isd,
                       const int* __restrict__ batch, int* bound, int* counts,
                       const float* __restrict__ W0, const float* __restrict__ W1,
                       const float* __restrict__ W2, ushort_t* Whi, ushort_t* Wlo) {
    int b = blockIdx.x, t = threadIdx.x;
    if (b < 196) {
        // in-wave prefix of bsum[0..chunk) ; chunk = b>>2 (256-blocks align in 1024-chunks)
        int chunk = b >> 2;
        int lane = t & 63;
        int v = (lane < chunk) ? bsum[lane] : 0;
        for (int o = 32; o > 0; o >>= 1) v += __shfl_down(v, o);
        int px = __shfl(v, 0);
        int i = b * 256 + t;
        if (i < N_NODES) {
            int r = rowp[i] + px;
            rowp[i] = r;
            nxt[i] = r;
            isd[i] = 1.0f / sqrtf((float)cnt[i] + 1.0f);
        }
    } else if (b == 196) {
        int g = t;
        if (g <= NGRAPH) {
            int lo = 0, hi = N_NODES;
            while (lo < hi) {
                int mid = (lo + hi) >> 1;
                if (batch[mid] < g) lo = mid + 1; else hi = mid;
            }
            bound[g] = lo;
        }
        __syncthreads();
        if (g < NGRAPH) counts[g] = bound[g + 1] - bound[g];
    } else {
        int gid = (b - 197) * 256 + t;          // 192*256 = 49152 items
        int l = gid / (32 * 512);
        int rem = gid - l * 32 * 512;
        int tile = rem >> 9;
        int p = rem & 511;
        int lane = p >> 3, j = p & 7;
        int kk = tile >> 3, c = tile & 7;
        int k = 32 * kk + (lane >> 4) * 8 + j;
        int n = 16 * c + (lane & 15);
        const float* W = (l == 0) ? W0 : (l == 1) ? W1 : W2;
        float x = W[k * 128 + n];
        ushort_t hi = f2bf(x);
        ushort_t lo = f2bf(x - bf2f(hi));
        Whi[l * 16384 + rem] = hi;
        Wlo[l * 16384 + rem] = lo;
    }
}

__global__ void k_fill(const int* __restrict__ src, const int* __restrict__ dst,
                       int* nxt, int* csr) {
    int i = blockIdx.x * 256 + threadIdx.x;
    if (i < N_EDGES) {
        int d = dst[i];
        int p = atomicAdd(&nxt[d], 1);
        csr[p] = src[i];
    }
}

// ---------------- fused layer: t = isd*(gather-sum) ; h = relu(t@W + b) -----
// aggregate-first (agg and W commute). 16 nodes/block, 4 waves.
// pre_scaled: input rows already carry isd (h' = isd*h). scale_out: write isd*val.
__global__ void k_layer(const float* __restrict__ In, const int* __restrict__ csr,
                        const int* __restrict__ rowp, const int* __restrict__ cnt,
                        const float* __restrict__ isd,
                        const ushort_t* __restrict__ Whi, const ushort_t* __restrict__ Wlo,
                        const float* __restrict__ bias, int pre_scaled, int scale_out,
                        float* __restrict__ Out) {
    __shared__ float T[16][132];
    int t = threadIdx.x, wv = t >> 6, lane = t & 63;

    // ---- gather phase: wave wv aggregates nodes (block*16 + wv*4 + r)
    for (int r = 0; r < 4; r++) {
        int i = blockIdx.x * 16 + wv * 4 + r;      // 3125*16 = 50000 exact
        int start = rowp[i];
        int m = cnt[i];
        float isdi = isd[i];
        float2 self = *(const float2*)(In + (size_t)i * 128 + lane * 2);
        float sfac = pre_scaled ? 1.0f : isdi;
        float a0x = sfac * self.x, a0y = sfac * self.y;
        float a1x = 0.f, a1y = 0.f, a2x = 0.f, a2y = 0.f, a3x = 0.f, a3y = 0.f;
        int e = 0;
        if (pre_scaled) {
            for (; e + 3 < m; e += 4) {
                int s0 = csr[start + e], s1 = csr[start + e + 1];
                int s2 = csr[start + e + 2], s3 = csr[start + e + 3];
                float2 v0 = *(const float2*)(In + (size_t)s0 * 128 + lane * 2);
                float2 v1 = *(const float2*)(In + (size_t)s1 * 128 + lane * 2);
                float2 v2 = *(const float2*)(In + (size_t)s2 * 128 + lane * 2);
                float2 v3 = *(const float2*)(In + (size_t)s3 * 128 + lane * 2);
                a0x += v0.x; a0y += v0.y; a1x += v1.x; a1y += v1.y;
                a2x += v2.x; a2y += v2.y; a3x += v3.x; a3y += v3.y;
            }
            for (; e < m; e++) {
                int s0 = csr[start + e];
                float2 v0 = *(const float2*)(In + (size_t)s0 * 128 + lane * 2);
                a0x += v0.x; a0y += v0.y;
            }
        } else {
            for (; e + 3 < m; e += 4) {
                int s0 = csr[start + e], s1 = csr[start + e + 1];
                int s2 = csr[start + e + 2], s3 = csr[start + e + 3];
                float d0 = isd[s0], d1 = isd[s1], d2 = isd[s2], d3 = isd[s3];
                float2 v0 = *(const float2*)(In + (size_t)s0 * 128 + lane * 2);
                float2 v1 = *(const float2*)(In + (size_t)s1 * 128 + lane * 2);
                float2 v2 = *(const float2*)(In + (size_t)s2 * 128 + lane * 2);
                float2 v3 = *(const float2*)(In + (size_t)s3 * 128 + lane * 2);
                a0x = fmaf(d0, v0.x, a0x); a0y = fmaf(d0, v0.y, a0y);
                a1x = fmaf(d1, v1.x, a1x); a1y = fmaf(d1, v1.y, a1y);
                a2x = fmaf(d2, v2.x, a2x); a2y = fmaf(d2, v2.y, a2y);
                a3x = fmaf(d3, v3.x, a3x); a3y = fmaf(d3, v3.y, a3y);
            }
            for (; e < m; e++) {
                int s0 = csr[start + e];
                float d0 = isd[s0];
                float2 v0 = *(const float2*)(In + (size_t)s0 * 128 + lane * 2);
                a0x = fmaf(d0, v0.x, a0x); a0y = fmaf(d0, v0.y, a0y);
            }
        }
        float sx = (a0x + a1x) + (a2x + a3x);
        float sy = (a0y + a1y) + (a2y + a3y);
        int lr = wv * 4 + r;
        T[lr][lane * 2] = isdi * sx;
        T[lr][lane * 2 + 1] = isdi * sy;
    }
    __syncthreads();

    // ---- MFMA phase: wave wv -> cols [wv*32, wv*32+32)
    int mrow = lane & 15, q = lane >> 4;
    f32x4 acc[2];
    acc[0] = (f32x4){0.f, 0.f, 0.f, 0.f};
    acc[1] = (f32x4){0.f, 0.f, 0.f, 0.f};
#pragma unroll
    for (int kk = 0; kk < 4; kk++) {
        const float* tp = &T[mrow][kk * 32 + q * 8];
        float4 p0 = *(const float4*)tp;
        float4 p1 = *(const float4*)(tp + 4);
        float av[8] = {p0.x, p0.y, p0.z, p0.w, p1.x, p1.y, p1.z, p1.w};
        bf16x8 ahi, alo;
#pragma unroll
        for (int j = 0; j < 8; j++) {
            ushort_t hbits = f2bf(av[j]);
            ahi[j] = (short)hbits;
            alo[j] = (short)f2bf(av[j] - bf2f(hbits));
        }
#pragma unroll
        for (int cl = 0; cl < 2; cl++) {
            int c = wv * 2 + cl;
            const bf16x8 bhi = *(const bf16x8*)(Whi + (((kk * 8 + c) * 64 + lane) << 3));
            const bf16x8 blo = *(const bf16x8*)(Wlo + (((kk * 8 + c) * 64 + lane) << 3));
            acc[cl] = __builtin_amdgcn_mfma_f32_16x16x32_bf16(ahi, bhi, acc[cl], 0, 0, 0);
            acc[cl] = __builtin_amdgcn_mfma_f32_16x16x32_bf16(alo, bhi, acc[cl], 0, 0, 0);
            acc[cl] = __builtin_amdgcn_mfma_f32_16x16x32_bf16(ahi, blo, acc[cl], 0, 0, 0);
        }
    }
    // epilogue: C/D col = mrow, row = q*4+rr (verified R10 mapping)
    int rb = blockIdx.x * 16 + q * 4;
    float osc[4];
#pragma unroll
    for (int rr = 0; rr < 4; rr++) osc[rr] = scale_out ? isd[rb + rr] : 1.0f;
#pragma unroll
    for (int cl = 0; cl < 2; cl++) {
        int col = (wv * 2 + cl) * 16 + mrow;
        float bcol = bias[col];
#pragma unroll
        for (int rr = 0; rr < 4; rr++) {
            float val = fmaxf(acc[cl][rr] + bcol, 0.f);
            Out[(size_t)(rb + rr) * 128 + col] = val * osc[rr];
        }
    }
}

// ---------------- pooling ----------------
__global__ void k_pool(const float* __restrict__ h, const int* __restrict__ batch,
                       float* sums, float* maxs) {
    int t = threadIdx.x;
    int n0 = blockIdx.x * 128;
    int nend = min(n0 + 128, N_NODES);
    int cur = batch[n0];
    float s = 0.f, mx = 0.f;
    for (int n = n0; n < nend; n++) {
        int g = batch[n];
        if (g != cur) {
            atomicAdd(&sums[cur * HID + t], s);
            atomicMax((int*)&maxs[cur * HID + t], __float_as_int(mx));
            s = 0.f; mx = 0.f; cur = g;
        }
        float v = h[(size_t)n * HID + t];
        s += v;
        mx = fmaxf(mx, v);
    }
    atomicAdd(&sums[cur * HID + t], s);
    atomicMax((int*)&maxs[cur * HID + t], __float_as_int(mx));
}

// ---------------- head ----------------
__global__ void k_final(const float* __restrict__ sums, const float* __restrict__ maxs,
                        const int* __restrict__ counts, const float* __restrict__ Wa,
                        const float* __restrict__ ba, float* __restrict__ out) {
    __shared__ float a[256];
    __shared__ float red[4];
    int g = blockIdx.x, t = threadIdx.x;
    float denom = fmaxf((float)counts[g], 1.f);
    float val = (t < 128) ? (sums[g * HID + t] / denom) : maxs[g * HID + (t - 128)];
    a[t] = val;
    out[NGRAPH * NCLS + g * 256 + t] = val;
    __syncthreads();
    for (int c = 0; c < NCLS; c++) {
        float p = a[t] * Wa[t * NCLS + c];
        for (int o = 32; o > 0; o >>= 1) p += __shfl_down(p, o);
        if ((t & 63) == 0) red[t >> 6] = p;
        __syncthreads();
        if (t == 0) {
            out[g * NCLS + c] = red[0] + red[1] + red[2] + red[3] + ba[c];
        }
        __syncthreads();
    }
}

extern "C" void kernel_launch(void* const* d_in, const int* in_sizes, int n_in,
                              void* d_out, int out_size, void* d_ws, size_t ws_size,
                              hipStream_t stream) {
    const float* x = (const float*)d_in[0];
    const int* ei = (const int*)d_in[1];
    const int* src = ei;
    const int* dst = ei + N_EDGES;
    const int* batch = (const int*)d_in[2];
    const float* W0 = (const float*)d_in[3];
    const float* b0 = (const float*)d_in[4];
    const float* W1 = (const float*)d_in[5];
    const float* b1 = (const float*)d_in[6];
    const float* W2 = (const float*)d_in[7];
    const float* b2 = (const float*)d_in[8];
    const float* Wa = (const float*)d_in[9];
    const float* ba = (const float*)d_in[10];
    float* out = (float*)d_out;

    char* ws = (char*)d_ws;
    float*    isd    = (float*)(ws + 0);           // 50000 f32
    int*      cnt    = (int*)(ws + 200192);        // 50000 i32
    int*      rowp   = (int*)(ws + 400384);        // 50000 i32
    int*      nxt    = (int*)(ws + 600576);        // 50000 i32
    int*      bsum   = (int*)(ws + 800768);        // 49 i32
    int*      bound  = (int*)(ws + 800968);        // 65 i32
    int*      csr    = (int*)(ws + 801280);        // 800000 i32
    int*      counts = (int*)(ws + 4001280);       // 64 i32
    float*    sums   = (float*)(ws + 4001536);     // 8192 f32
    float*    maxs   = (float*)(ws + 4034304);     // 8192 f32
    float*    h      = (float*)(ws + 4067072);     // 50000x128 f32
    float*    hp     = (float*)(ws + 29667072);    // 50000x128 f32
    ushort_t* Whi    = (ushort_t*)(ws + 55267072); // 3*16384 bf16
    ushort_t* Wlo    = (ushort_t*)(ws + 55365376); // 3*16384 bf16

    hipMemsetAsync(cnt, 0, N_NODES * 4, stream);
    hipMemsetAsync(sums, 0, NGRAPH * HID * 4, stream);
    hipMemsetAsync(maxs, 0, NGRAPH * HID * 4, stream);

    k_count_edges<<<(N_EDGES + 255) / 256, 256, 0, stream>>>(dst, cnt);
    k_scanA<<<49, 1024, 0, stream>>>(cnt, rowp, bsum);
    k_post<<<389, 256, 0, stream>>>(rowp, bsum, nxt, cnt, isd, batch, bound, counts,
                                    W0, W1, W2, Whi, Wlo);
    k_fill<<<(N_EDGES + 255) / 256, 256, 0, stream>>>(src, dst, nxt, csr);

    // aggregate-first fused layers: x ->(agg,W0)-> h' ->(agg,W1)-> hp' ->(agg,W2)-> h
    k_layer<<<3125, 256, 0, stream>>>(x, csr, rowp, cnt, isd, Whi, Wlo, b0, 0, 1, h);
    k_layer<<<3125, 256, 0, stream>>>(h, csr, rowp, cnt, isd, Whi + 16384, Wlo + 16384, b1, 1, 1, hp);
    k_layer<<<3125, 256, 0, stream>>>(hp, csr, rowp, cnt, isd, Whi + 32768, Wlo + 32768, b2, 1, 0, h);

    k_pool<<<391, 128, 0, stream>>>(h, batch, sums, maxs);
    k_final<<<NGRAPH, 256, 0, stream>>>(sums, maxs, counts, Wa, ba, out);
}

// Round 12
// 382.868 us; speedup vs baseline: 1.9327x; 1.1121x over previous
//
#include <hip/hip_runtime.h>
#include <stdint.h>

#define N_NODES 50000
#define N_EDGES 800000
#define HID 128
#define NCLS 10
#define NGRAPH 64
#define CAP 64   // bucket capacity; deg ~ Poisson(16), P(max>64) < 1e-20

typedef unsigned short ushort_t;
typedef __attribute__((ext_vector_type(8))) short bf16x8;
typedef __attribute__((ext_vector_type(4))) float f32x4;

__device__ __forceinline__ ushort_t f2bf(float f) {
    union { float f; unsigned int i; } v; v.f = f;
    unsigned int u = v.i;
    return (ushort_t)((u + 0x7FFFu + ((u >> 16) & 1u)) >> 16);
}
__device__ __forceinline__ float bf2f(ushort_t u) {
    union { unsigned int i; float f; } v; v.i = ((unsigned int)u) << 16; return v.f;
}

// ---- fused: zero cnt/sums/maxs (blocks 0..195) + bounds (196) + wsplit (197..388)
__global__ void k_zero(int* cnt, float* sums, float* maxs,
                       const int* __restrict__ batch, int* bound, int* counts,
                       const float* __restrict__ W0, const float* __restrict__ W1,
                       const float* __restrict__ W2, ushort_t* Whi, ushort_t* Wlo) {
    int b = blockIdx.x, t = threadIdx.x;
    if (b < 196) {
        int i = b * 256 + t;
        if (i < N_NODES) cnt[i] = 0;
        if (i < NGRAPH * HID) { sums[i] = 0.f; maxs[i] = 0.f; }
    } else if (b == 196) {
        int g = t;
        if (g <= NGRAPH) {
            int lo = 0, hi = N_NODES;
            while (lo < hi) {
                int mid = (lo + hi) >> 1;
                if (batch[mid] < g) lo = mid + 1; else hi = mid;
            }
            bound[g] = lo;
        }
        __syncthreads();
        if (g < NGRAPH) counts[g] = bound[g + 1] - bound[g];
    } else {
        int gid = (b - 197) * 256 + t;          // 192*256 = 49152 items
        int l = gid / (32 * 512);
        int rem = gid - l * 32 * 512;
        int tile = rem >> 9;
        int p = rem & 511;
        int lane = p >> 3, j = p & 7;
        int kk = tile >> 3, c = tile & 7;
        int k = 32 * kk + (lane >> 4) * 8 + j;
        int n = 16 * c + (lane & 15);
        const float* W = (l == 0) ? W0 : (l == 1) ? W1 : W2;
        float x = W[k * 128 + n];
        ushort_t hi = f2bf(x);
        ushort_t lo = f2bf(x - bf2f(hi));
        Whi[l * 16384 + rem] = hi;
        Wlo[l * 16384 + rem] = lo;
    }
}

// ---- one-pass bucket-CSR fill: csr16[d*CAP + slot] = src (ushort node ids)
__global__ void k_fill(const int* __restrict__ src, const int* __restrict__ dst,
                       int* cnt, ushort_t* csr16) {
    int i = blockIdx.x * 256 + threadIdx.x;
    if (i < N_EDGES) {
        int d = dst[i];
        int slot = atomicAdd(&cnt[d], 1);
        if (slot < CAP) csr16[d * CAP + slot] = (ushort_t)src[i];
    }
}

// ---------------- fused layer: t = isd*(gather-sum) ; h = relu(t@W + b) -----
// aggregate-first. 16 nodes/block, 4 waves. isd computed on-the-fly from cnt.
__global__ void k_layer(const float* __restrict__ In, const ushort_t* __restrict__ csr16,
                        const int* __restrict__ cnt,
                        const ushort_t* __restrict__ Whi, const ushort_t* __restrict__ Wlo,
                        const float* __restrict__ bias, int pre_scaled, int scale_out,
                        float* __restrict__ Out) {
    __shared__ float T[16][132];
    int t = threadIdx.x, wv = t >> 6, lane = t & 63;

    // ---- gather phase: wave wv aggregates nodes (block*16 + wv*4 + r)
    for (int r = 0; r < 4; r++) {
        int i = blockIdx.x * 16 + wv * 4 + r;      // 3125*16 = 50000 exact
        int ci = cnt[i];
        int m = min(ci, CAP);
        float isdi = rsqrtf((float)ci + 1.0f);
        const ushort_t* row = csr16 + (size_t)i * CAP;
        float2 self = *(const float2*)(In + (size_t)i * 128 + lane * 2);
        float sfac = pre_scaled ? 1.0f : isdi;
        float a0x = sfac * self.x, a0y = sfac * self.y;
        float a1x = 0.f, a1y = 0.f, a2x = 0.f, a2y = 0.f, a3x = 0.f, a3y = 0.f;
        int e = 0;
        if (pre_scaled) {
            for (; e + 3 < m; e += 4) {
                ushort4 ss = *(const ushort4*)(row + e);
                float2 v0 = *(const float2*)(In + (size_t)ss.x * 128 + lane * 2);
                float2 v1 = *(const float2*)(In + (size_t)ss.y * 128 + lane * 2);
                float2 v2 = *(const float2*)(In + (size_t)ss.z * 128 + lane * 2);
                float2 v3 = *(const float2*)(In + (size_t)ss.w * 128 + lane * 2);
                a0x += v0.x; a0y += v0.y; a1x += v1.x; a1y += v1.y;
                a2x += v2.x; a2y += v2.y; a3x += v3.x; a3y += v3.y;
            }
            for (; e < m; e++) {
                int s0 = row[e];
                float2 v0 = *(const float2*)(In + (size_t)s0 * 128 + lane * 2);
                a0x += v0.x; a0y += v0.y;
            }
        } else {
            for (; e + 3 < m; e += 4) {
                ushort4 ss = *(const ushort4*)(row + e);
                float d0 = rsqrtf((float)cnt[ss.x] + 1.0f);
                float d1 = rsqrtf((float)cnt[ss.y] + 1.0f);
                float d2 = rsqrtf((float)cnt[ss.z] + 1.0f);
                float d3 = rsqrtf((float)cnt[ss.w] + 1.0f);
                float2 v0 = *(const float2*)(In + (size_t)ss.x * 128 + lane * 2);
                float2 v1 = *(const float2*)(In + (size_t)ss.y * 128 + lane * 2);
                float2 v2 = *(const float2*)(In + (size_t)ss.z * 128 + lane * 2);
                float2 v3 = *(const float2*)(In + (size_t)ss.w * 128 + lane * 2);
                a0x = fmaf(d0, v0.x, a0x); a0y = fmaf(d0, v0.y, a0y);
                a1x = fmaf(d1, v1.x, a1x); a1y = fmaf(d1, v1.y, a1y);
                a2x = fmaf(d2, v2.x, a2x); a2y = fmaf(d2, v2.y, a2y);
                a3x = fmaf(d3, v3.x, a3x); a3y = fmaf(d3, v3.y, a3y);
            }
            for (; e < m; e++) {
                int s0 = row[e];
                float d0 = rsqrtf((float)cnt[s0] + 1.0f);
                float2 v0 = *(const float2*)(In + (size_t)s0 * 128 + lane * 2);
                a0x = fmaf(d0, v0.x, a0x); a0y = fmaf(d0, v0.y, a0y);
            }
        }
        float sx = (a0x + a1x) + (a2x + a3x);
        float sy = (a0y + a1y) + (a2y + a3y);
        int lr = wv * 4 + r;
        T[lr][lane * 2] = isdi * sx;
        T[lr][lane * 2 + 1] = isdi * sy;
    }
    __syncthreads();

    // ---- MFMA phase: wave wv -> cols [wv*32, wv*32+32)
    int mrow = lane & 15, q = lane >> 4;
    f32x4 acc[2];
    acc[0] = (f32x4){0.f, 0.f, 0.f, 0.f};
    acc[1] = (f32x4){0.f, 0.f, 0.f, 0.f};
#pragma unroll
    for (int kk = 0; kk < 4; kk++) {
        const float* tp = &T[mrow][kk * 32 + q * 8];
        float4 p0 = *(const float4*)tp;
        float4 p1 = *(const float4*)(tp + 4);
        float av[8] = {p0.x, p0.y, p0.z, p0.w, p1.x, p1.y, p1.z, p1.w};
        bf16x8 ahi, alo;
#pragma unroll
        for (int j = 0; j < 8; j++) {
            ushort_t hbits = f2bf(av[j]);
            ahi[j] = (short)hbits;
            alo[j] = (short)f2bf(av[j] - bf2f(hbits));
        }
#pragma unroll
        for (int cl = 0; cl < 2; cl++) {
            int c = wv * 2 + cl;
            const bf16x8 bhi = *(const bf16x8*)(Whi + (((kk * 8 + c) * 64 + lane) << 3));
            const bf16x8 blo = *(const bf16x8*)(Wlo + (((kk * 8 + c) * 64 + lane) << 3));
            acc[cl] = __builtin_amdgcn_mfma_f32_16x16x32_bf16(ahi, bhi, acc[cl], 0, 0, 0);
            acc[cl] = __builtin_amdgcn_mfma_f32_16x16x32_bf16(alo, bhi, acc[cl], 0, 0, 0);
            acc[cl] = __builtin_amdgcn_mfma_f32_16x16x32_bf16(ahi, blo, acc[cl], 0, 0, 0);
        }
    }
    // epilogue: C/D col = mrow, row = q*4+rr
    int rb = blockIdx.x * 16 + q * 4;
    float osc[4];
#pragma unroll
    for (int rr = 0; rr < 4; rr++)
        osc[rr] = scale_out ? rsqrtf((float)cnt[rb + rr] + 1.0f) : 1.0f;
#pragma unroll
    for (int cl = 0; cl < 2; cl++) {
        int col = (wv * 2 + cl) * 16 + mrow;
        float bcol = bias[col];
#pragma unroll
        for (int rr = 0; rr < 4; rr++) {
            float val = fmaxf(acc[cl][rr] + bcol, 0.f);
            Out[(size_t)(rb + rr) * 128 + col] = val * osc[rr];
        }
    }
}

// ---------------- pooling ----------------
__global__ void k_pool(const float* __restrict__ h, const int* __restrict__ batch,
                       float* sums, float* maxs) {
    int t = threadIdx.x;
    int n0 = blockIdx.x * 128;
    int nend = min(n0 + 128, N_NODES);
    int cur = batch[n0];
    float s = 0.f, mx = 0.f;
    for (int n = n0; n < nend; n++) {
        int g = batch[n];
        if (g != cur) {
            atomicAdd(&sums[cur * HID + t], s);
            atomicMax((int*)&maxs[cur * HID + t], __float_as_int(mx));
            s = 0.f; mx = 0.f; cur = g;
        }
        float v = h[(size_t)n * HID + t];
        s += v;
        mx = fmaxf(mx, v);
    }
    atomicAdd(&sums[cur * HID + t], s);
    atomicMax((int*)&maxs[cur * HID + t], __float_as_int(mx));
}

// ---------------- head ----------------
__global__ void k_final(const float* __restrict__ sums, const float* __restrict__ maxs,
                        const int* __restrict__ counts, const float* __restrict__ Wa,
                        const float* __restrict__ ba, float* __restrict__ out) {
    __shared__ float a[256];
    __shared__ float red[4];
    int g = blockIdx.x, t = threadIdx.x;
    float denom = fmaxf((float)counts[g], 1.f);
    float val = (t < 128) ? (sums[g * HID + t] / denom) : maxs[g * HID + (t - 128)];
    a[t] = val;
    out[NGRAPH * NCLS + g * 256 + t] = val;
    __syncthreads();
    for (int c = 0; c < NCLS; c++) {
        float p = a[t] * Wa[t * NCLS + c];
        for (int o = 32; o > 0; o >>= 1) p += __shfl_down(p, o);
        if ((t & 63) == 0) red[t >> 6] = p;
        __syncthreads();
        if (t == 0) {
            out[g * NCLS + c] = red[0] + red[1] + red[2] + red[3] + ba[c];
        }
        __syncthreads();
    }
}

extern "C" void kernel_launch(void* const* d_in, const int* in_sizes, int n_in,
                              void* d_out, int out_size, void* d_ws, size_t ws_size,
                              hipStream_t stream) {
    const float* x = (const float*)d_in[0];
    const int* ei = (const int*)d_in[1];
    const int* src = ei;
    const int* dst = ei + N_EDGES;
    const int* batch = (const int*)d_in[2];
    const float* W0 = (const float*)d_in[3];
    const float* b0 = (const float*)d_in[4];
    const float* W1 = (const float*)d_in[5];
    const float* b1 = (const float*)d_in[6];
    const float* W2 = (const float*)d_in[7];
    const float* b2 = (const float*)d_in[8];
    const float* Wa = (const float*)d_in[9];
    const float* ba = (const float*)d_in[10];
    float* out = (float*)d_out;

    char* ws = (char*)d_ws;
    int*      cnt    = (int*)(ws + 0);             // 50000 i32
    int*      bound  = (int*)(ws + 200192);        // 65 i32
    int*      counts = (int*)(ws + 200576);        // 64 i32
    float*    sums   = (float*)(ws + 200832);      // 8192 f32
    float*    maxs   = (float*)(ws + 233600);      // 8192 f32
    ushort_t* Whi    = (ushort_t*)(ws + 266368);   // 3*16384 bf16
    ushort_t* Wlo    = (ushort_t*)(ws + 364672);   // 3*16384 bf16
    ushort_t* csr16  = (ushort_t*)(ws + 462976);   // 50000*64 u16 (6.4 MB)
    float*    h      = (float*)(ws + 6862976);     // 50000x128 f32
    float*    hp     = (float*)(ws + 32462976);    // 50000x128 f32
    // total 58,062,976 B

    k_zero<<<389, 256, 0, stream>>>(cnt, sums, maxs, batch, bound, counts,
                                    W0, W1, W2, Whi, Wlo);
    k_fill<<<3125, 256, 0, stream>>>(src, dst, cnt, csr16);

    // aggregate-first fused layers
    k_layer<<<3125, 256, 0, stream>>>(x, csr16, cnt, Whi, Wlo, b0, 0, 1, h);
    k_layer<<<3125, 256, 0, stream>>>(h, csr16, cnt, Whi + 16384, Wlo + 16384, b1, 1, 1, hp);
    k_layer<<<3125, 256, 0, stream>>>(hp, csr16, cnt, Whi + 32768, Wlo + 32768, b2, 1, 0, h);

    k_pool<<<391, 128, 0, stream>>>(h, batch, sums, maxs);
    k_final<<<NGRAPH, 256, 0, stream>>>(sums, maxs, counts, Wa, ba, out);
}

// Round 13
// 340.211 us; speedup vs baseline: 2.1750x; 1.1254x over previous
//
#include <hip/hip_runtime.h>
#include <stdint.h>

#define N_NODES 50000
#define N_EDGES 800000
#define HID 128
#define NCLS 10
#define NGRAPH 64
#define CAP 64   // bucket capacity; deg ~ Poisson(16), P(max>64) < 1e-20

typedef unsigned short ushort_t;
typedef __attribute__((ext_vector_type(8))) short bf16x8;
typedef __attribute__((ext_vector_type(4))) float f32x4;

__device__ __forceinline__ ushort_t f2bf(float f) {
    union { float f; unsigned int i; } v; v.f = f;
    unsigned int u = v.i;
    return (ushort_t)((u + 0x7FFFu + ((u >> 16) & 1u)) >> 16);
}
__device__ __forceinline__ float bf2f(ushort_t u) {
    union { unsigned int i; float f; } v; v.i = ((unsigned int)u) << 16; return v.f;
}

// ---- fused: zero cnt/sums/maxs (blocks 0..195) + bounds (196) + wsplit (197..388)
__global__ void k_zero(int* cnt, float* sums, float* maxs,
                       const int* __restrict__ batch, int* bound, int* counts,
                       const float* __restrict__ W0, const float* __restrict__ W1,
                       const float* __restrict__ W2, ushort_t* Whi, ushort_t* Wlo) {
    int b = blockIdx.x, t = threadIdx.x;
    if (b < 196) {
        int i = b * 256 + t;
        if (i < N_NODES) cnt[i] = 0;
        if (i < NGRAPH * HID) { sums[i] = 0.f; maxs[i] = 0.f; }
    } else if (b == 196) {
        int g = t;
        if (g <= NGRAPH) {
            int lo = 0, hi = N_NODES;
            while (lo < hi) {
                int mid = (lo + hi) >> 1;
                if (batch[mid] < g) lo = mid + 1; else hi = mid;
            }
            bound[g] = lo;
        }
        __syncthreads();
        if (g < NGRAPH) counts[g] = bound[g + 1] - bound[g];
    } else {
        int gid = (b - 197) * 256 + t;          // 192*256 = 49152 items
        int l = gid / (32 * 512);
        int rem = gid - l * 32 * 512;
        int tile = rem >> 9;
        int p = rem & 511;
        int lane = p >> 3, j = p & 7;
        int kk = tile >> 3, c = tile & 7;
        int k = 32 * kk + (lane >> 4) * 8 + j;
        int n = 16 * c + (lane & 15);
        const float* W = (l == 0) ? W0 : (l == 1) ? W1 : W2;
        float x = W[k * 128 + n];
        ushort_t hi = f2bf(x);
        ushort_t lo = f2bf(x - bf2f(hi));
        Whi[l * 16384 + rem] = hi;
        Wlo[l * 16384 + rem] = lo;
    }
}

// ---- one-pass bucket-CSR fill, 4 edges/thread for atomic MLP ----
__global__ void k_fill(const int* __restrict__ src, const int* __restrict__ dst,
                       int* cnt, ushort_t* csr16) {
    int base = (blockIdx.x * 256 + threadIdx.x) * 4;
    if (base + 3 < N_EDGES) {
        int4 d4 = *(const int4*)(dst + base);
        int4 s4 = *(const int4*)(src + base);
        int p0 = atomicAdd(&cnt[d4.x], 1);
        int p1 = atomicAdd(&cnt[d4.y], 1);
        int p2 = atomicAdd(&cnt[d4.z], 1);
        int p3 = atomicAdd(&cnt[d4.w], 1);
        if (p0 < CAP) csr16[d4.x * CAP + p0] = (ushort_t)s4.x;
        if (p1 < CAP) csr16[d4.y * CAP + p1] = (ushort_t)s4.y;
        if (p2 < CAP) csr16[d4.z * CAP + p2] = (ushort_t)s4.z;
        if (p3 < CAP) csr16[d4.w * CAP + p3] = (ushort_t)s4.w;
    } else {
        for (int i = base; i < N_EDGES; i++) {
            int d = dst[i];
            int slot = atomicAdd(&cnt[d], 1);
            if (slot < CAP) csr16[d * CAP + slot] = (ushort_t)src[i];
        }
    }
}

// ---------------- fused layer: t = isd*(gather-sum) ; h = relu(t@W + b) -----
// aggregate-first. 16 nodes/block, 4 waves. pool=1 (layer 3): skip Out write,
// block-reduce rows in LDS and atomically merge into sums/maxs.
__global__ void k_layer(const float* __restrict__ In, const ushort_t* __restrict__ csr16,
                        const int* __restrict__ cnt,
                        const ushort_t* __restrict__ Whi, const ushort_t* __restrict__ Wlo,
                        const float* __restrict__ bias, int pre_scaled, int scale_out,
                        int pool, const int* __restrict__ batch,
                        float* sums, float* maxs, float* __restrict__ Out) {
    __shared__ float T[16][132];
    __shared__ int sg[16];
    int t = threadIdx.x, wv = t >> 6, lane = t & 63;
    if (pool && t < 16) sg[t] = batch[blockIdx.x * 16 + t];

    // ---- gather phase: wave wv aggregates nodes (block*16 + wv*4 + r)
    for (int r = 0; r < 4; r++) {
        int i = blockIdx.x * 16 + wv * 4 + r;      // 3125*16 = 50000 exact
        int ci = cnt[i];
        int m = min(ci, CAP);
        float isdi = rsqrtf((float)ci + 1.0f);
        const ushort_t* row = csr16 + (size_t)i * CAP;
        float2 self = *(const float2*)(In + (size_t)i * 128 + lane * 2);
        float sfac = pre_scaled ? 1.0f : isdi;
        float a0x = sfac * self.x, a0y = sfac * self.y;
        float a1x = 0.f, a1y = 0.f, a2x = 0.f, a2y = 0.f, a3x = 0.f, a3y = 0.f;
        int e = 0;
        if (pre_scaled) {
            for (; e + 3 < m; e += 4) {
                ushort4 ss = *(const ushort4*)(row + e);
                float2 v0 = *(const float2*)(In + (size_t)ss.x * 128 + lane * 2);
                float2 v1 = *(const float2*)(In + (size_t)ss.y * 128 + lane * 2);
                float2 v2 = *(const float2*)(In + (size_t)ss.z * 128 + lane * 2);
                float2 v3 = *(const float2*)(In + (size_t)ss.w * 128 + lane * 2);
                a0x += v0.x; a0y += v0.y; a1x += v1.x; a1y += v1.y;
                a2x += v2.x; a2y += v2.y; a3x += v3.x; a3y += v3.y;
            }
            for (; e < m; e++) {
                int s0 = row[e];
                float2 v0 = *(const float2*)(In + (size_t)s0 * 128 + lane * 2);
                a0x += v0.x; a0y += v0.y;
            }
        } else {
            for (; e + 3 < m; e += 4) {
                ushort4 ss = *(const ushort4*)(row + e);
                float d0 = rsqrtf((float)cnt[ss.x] + 1.0f);
                float d1 = rsqrtf((float)cnt[ss.y] + 1.0f);
                float d2 = rsqrtf((float)cnt[ss.z] + 1.0f);
                float d3 = rsqrtf((float)cnt[ss.w] + 1.0f);
                float2 v0 = *(const float2*)(In + (size_t)ss.x * 128 + lane * 2);
                float2 v1 = *(const float2*)(In + (size_t)ss.y * 128 + lane * 2);
                float2 v2 = *(const float2*)(In + (size_t)ss.z * 128 + lane * 2);
                float2 v3 = *(const float2*)(In + (size_t)ss.w * 128 + lane * 2);
                a0x = fmaf(d0, v0.x, a0x); a0y = fmaf(d0, v0.y, a0y);
                a1x = fmaf(d1, v1.x, a1x); a1y = fmaf(d1, v1.y, a1y);
                a2x = fmaf(d2, v2.x, a2x); a2y = fmaf(d2, v2.y, a2y);
                a3x = fmaf(d3, v3.x, a3x); a3y = fmaf(d3, v3.y, a3y);
            }
            for (; e < m; e++) {
                int s0 = row[e];
                float d0 = rsqrtf((float)cnt[s0] + 1.0f);
                float2 v0 = *(const float2*)(In + (size_t)s0 * 128 + lane * 2);
                a0x = fmaf(d0, v0.x, a0x); a0y = fmaf(d0, v0.y, a0y);
            }
        }
        float sx = (a0x + a1x) + (a2x + a3x);
        float sy = (a0y + a1y) + (a2y + a3y);
        int lr = wv * 4 + r;
        T[lr][lane * 2] = isdi * sx;
        T[lr][lane * 2 + 1] = isdi * sy;
    }
    __syncthreads();

    // ---- MFMA phase: wave wv -> cols [wv*32, wv*32+32)
    int mrow = lane & 15, q = lane >> 4;
    f32x4 acc[2];
    acc[0] = (f32x4){0.f, 0.f, 0.f, 0.f};
    acc[1] = (f32x4){0.f, 0.f, 0.f, 0.f};
#pragma unroll
    for (int kk = 0; kk < 4; kk++) {
        const float* tp = &T[mrow][kk * 32 + q * 8];
        float4 p0 = *(const float4*)tp;
        float4 p1 = *(const float4*)(tp + 4);
        float av[8] = {p0.x, p0.y, p0.z, p0.w, p1.x, p1.y, p1.z, p1.w};
        bf16x8 ahi, alo;
#pragma unroll
        for (int j = 0; j < 8; j++) {
            ushort_t hbits = f2bf(av[j]);
            ahi[j] = (short)hbits;
            alo[j] = (short)f2bf(av[j] - bf2f(hbits));
        }
#pragma unroll
        for (int cl = 0; cl < 2; cl++) {
            int c = wv * 2 + cl;
            const bf16x8 bhi = *(const bf16x8*)(Whi + (((kk * 8 + c) * 64 + lane) << 3));
            const bf16x8 blo = *(const bf16x8*)(Wlo + (((kk * 8 + c) * 64 + lane) << 3));
            acc[cl] = __builtin_amdgcn_mfma_f32_16x16x32_bf16(ahi, bhi, acc[cl], 0, 0, 0);
            acc[cl] = __builtin_amdgcn_mfma_f32_16x16x32_bf16(alo, bhi, acc[cl], 0, 0, 0);
            acc[cl] = __builtin_amdgcn_mfma_f32_16x16x32_bf16(ahi, blo, acc[cl], 0, 0, 0);
        }
    }
    // epilogue: C/D col = mrow, row = q*4+rr
    int rb = blockIdx.x * 16 + q * 4;
    if (!pool) {
        float osc[4];
#pragma unroll
        for (int rr = 0; rr < 4; rr++)
            osc[rr] = scale_out ? rsqrtf((float)cnt[rb + rr] + 1.0f) : 1.0f;
#pragma unroll
        for (int cl = 0; cl < 2; cl++) {
            int col = (wv * 2 + cl) * 16 + mrow;
            float bcol = bias[col];
#pragma unroll
            for (int rr = 0; rr < 4; rr++) {
                float val = fmaxf(acc[cl][rr] + bcol, 0.f);
                Out[(size_t)(rb + rr) * 128 + col] = val * osc[rr];
            }
        }
    } else {
        // write relu'd values back into T (rows x feats), then block pool-reduce
        __syncthreads();   // all waves done reading T
#pragma unroll
        for (int cl = 0; cl < 2; cl++) {
            int col = (wv * 2 + cl) * 16 + mrow;
            float bcol = bias[col];
#pragma unroll
            for (int rr = 0; rr < 4; rr++)
                T[q * 4 + rr][col] = fmaxf(acc[cl][rr] + bcol, 0.f);
        }
        __syncthreads();
        int f = t & 127, half = t >> 7;   // half 0: sums, half 1: maxs
        int cur = sg[0];
        float s = 0.f, mx = 0.f;
        for (int r = 0; r < 16; r++) {
            int g = sg[r];
            if (g != cur) {
                if (half == 0) atomicAdd(&sums[cur * HID + f], s);
                else atomicMax((int*)&maxs[cur * HID + f], __float_as_int(mx));
                s = 0.f; mx = 0.f; cur = g;
            }
            float v = T[r][f];
            s += v;
            mx = fmaxf(mx, v);
        }
        if (half == 0) atomicAdd(&sums[cur * HID + f], s);
        else atomicMax((int*)&maxs[cur * HID + f], __float_as_int(mx));
    }
}

// ---------------- head ----------------
__global__ void k_final(const float* __restrict__ sums, const float* __restrict__ maxs,
                        const int* __restrict__ counts, const float* __restrict__ Wa,
                        const float* __restrict__ ba, float* __restrict__ out) {
    __shared__ float a[256];
    __shared__ float red[4];
    int g = blockIdx.x, t = threadIdx.x;
    float denom = fmaxf((float)counts[g], 1.f);
    float val = (t < 128) ? (sums[g * HID + t] / denom) : maxs[g * HID + (t - 128)];
    a[t] = val;
    out[NGRAPH * NCLS + g * 256 + t] = val;
    __syncthreads();
    for (int c = 0; c < NCLS; c++) {
        float p = a[t] * Wa[t * NCLS + c];
        for (int o = 32; o > 0; o >>= 1) p += __shfl_down(p, o);
        if ((t & 63) == 0) red[t >> 6] = p;
        __syncthreads();
        if (t == 0) {
            out[g * NCLS + c] = red[0] + red[1] + red[2] + red[3] + ba[c];
        }
        __syncthreads();
    }
}

extern "C" void kernel_launch(void* const* d_in, const int* in_sizes, int n_in,
                              void* d_out, int out_size, void* d_ws, size_t ws_size,
                              hipStream_t stream) {
    const float* x = (const float*)d_in[0];
    const int* ei = (const int*)d_in[1];
    const int* src = ei;
    const int* dst = ei + N_EDGES;
    const int* batch = (const int*)d_in[2];
    const float* W0 = (const float*)d_in[3];
    const float* b0 = (const float*)d_in[4];
    const float* W1 = (const float*)d_in[5];
    const float* b1 = (const float*)d_in[6];
    const float* W2 = (const float*)d_in[7];
    const float* b2 = (const float*)d_in[8];
    const float* Wa = (const float*)d_in[9];
    const float* ba = (const float*)d_in[10];
    float* out = (float*)d_out;

    char* ws = (char*)d_ws;
    int*      cnt    = (int*)(ws + 0);             // 50000 i32
    int*      bound  = (int*)(ws + 200192);        // 65 i32
    int*      counts = (int*)(ws + 200576);        // 64 i32
    float*    sums   = (float*)(ws + 200832);      // 8192 f32
    float*    maxs   = (float*)(ws + 233600);      // 8192 f32
    ushort_t* Whi    = (ushort_t*)(ws + 266368);   // 3*16384 bf16
    ushort_t* Wlo    = (ushort_t*)(ws + 364672);   // 3*16384 bf16
    ushort_t* csr16  = (ushort_t*)(ws + 462976);   // 50000*64 u16 (6.4 MB)
    float*    h      = (float*)(ws + 6862976);     // 50000x128 f32
    float*    hp     = (float*)(ws + 32462976);    // 50000x128 f32
    // total 58,062,976 B

    k_zero<<<389, 256, 0, stream>>>(cnt, sums, maxs, batch, bound, counts,
                                    W0, W1, W2, Whi, Wlo);
    k_fill<<<782, 256, 0, stream>>>(src, dst, cnt, csr16);

    // aggregate-first fused layers; layer 3 pools in-kernel (no h3 write)
    k_layer<<<3125, 256, 0, stream>>>(x, csr16, cnt, Whi, Wlo, b0, 0, 1,
                                      0, batch, sums, maxs, h);
    k_layer<<<3125, 256, 0, stream>>>(h, csr16, cnt, Whi + 16384, Wlo + 16384, b1, 1, 1,
                                      0, batch, sums, maxs, hp);
    k_layer<<<3125, 256, 0, stream>>>(hp, csr16, cnt, Whi + 32768, Wlo + 32768, b2, 1, 0,
                                      1, batch, sums, maxs, h);

    k_final<<<NGRAPH, 256, 0, stream>>>(sums, maxs, counts, Wa, ba, out);
}